// Round 1
// baseline (1334.493 us; speedup 1.0000x reference)
//
#include <hip/hip_runtime.h>
#include <hip/hip_bf16.h>

#define CB 32
#define CN 1024
#define CE 512
#define CD 300

// ---------- embedding gather: X[r,:] = emb[idx[r],:] ----------
__global__ void k_embed(const int* __restrict__ idx, const float* __restrict__ emb,
                        float* __restrict__ X) {
    int gid = blockIdx.x * blockDim.x + threadIdx.x;
    const int total = CB * CN * 75;   // 75 float4 per 300-float row
    if (gid >= total) return;
    int r = gid / 75, c = gid % 75;
    int e = idx[r];
    reinterpret_cast<float4*>(X)[(size_t)r * 75 + c] =
        reinterpret_cast<const float4*>(emb)[(size_t)e * 75 + c];
}

// ---------- transpose HT [B,E,N] int -> HTt [B,N,E] u8 ----------
__global__ void k_transpose(const int* __restrict__ HT, unsigned char* __restrict__ HTt) {
    __shared__ int tile[32][33];
    int b = blockIdx.z;
    int e0 = blockIdx.x * 32, n0 = blockIdx.y * 32;
    int tx = threadIdx.x, ty = threadIdx.y;
    for (int i = ty; i < 32; i += 8)
        tile[i][tx] = HT[((size_t)b * CE + e0 + i) * CN + n0 + tx];
    __syncthreads();
    for (int i = ty; i < 32; i += 8)
        HTt[((size_t)b * CN + n0 + i) * CE + e0 + tx] = (unsigned char)(tile[tx][i] > 0 ? 1 : 0);
}

// ---------- C[M,300] = A[M,300] @ W[300,300], M % 64 == 0 ----------
__global__ __launch_bounds__(256) void k_gemm300(const float* __restrict__ A,
                                                 const float* __restrict__ W,
                                                 float* __restrict__ C, int M) {
    __shared__ float As[64][20];
    __shared__ float Ws[16][68];
    int tid = threadIdx.x;
    int n0 = blockIdx.x * 64, m0 = blockIdx.y * 64;
    int tx = tid & 15, ty = tid >> 4;
    int la_r = tid >> 2, la_c = (tid & 3) << 2;
    int lw_r = tid >> 4, lw_c = (tid & 15) << 2;
    float acc[4][4] = {};
    for (int k0 = 0; k0 < CD; k0 += 16) {
        {   // A tile 64x16
            int kc = k0 + la_c;
            const float* Ap = A + (size_t)(m0 + la_r) * CD + kc;
            float4 av;
            if (kc + 3 < CD) av = *reinterpret_cast<const float4*>(Ap);
            else {
                av.x = kc     < CD ? Ap[0] : 0.f;
                av.y = kc + 1 < CD ? Ap[1] : 0.f;
                av.z = kc + 2 < CD ? Ap[2] : 0.f;
                av.w = 0.f;
            }
            *reinterpret_cast<float4*>(&As[la_r][la_c]) = av;
        }
        {   // W tile 16x64
            int kr = k0 + lw_r;
            float4 wv = {0.f, 0.f, 0.f, 0.f};
            if (kr < CD) {
                const float* Wp = W + (size_t)kr * CD + n0 + lw_c;
                if (n0 + lw_c + 3 < CD) wv = *reinterpret_cast<const float4*>(Wp);
                else {
                    if (n0 + lw_c     < CD) wv.x = Wp[0];
                    if (n0 + lw_c + 1 < CD) wv.y = Wp[1];
                    if (n0 + lw_c + 2 < CD) wv.z = Wp[2];
                }
            }
            *reinterpret_cast<float4*>(&Ws[lw_r][lw_c]) = wv;
        }
        __syncthreads();
#pragma unroll
        for (int k = 0; k < 16; ++k) {
            float av[4];
#pragma unroll
            for (int i = 0; i < 4; ++i) av[i] = As[ty * 4 + i][k];
            float4 bv = *reinterpret_cast<const float4*>(&Ws[k][tx * 4]);
            float bb[4] = {bv.x, bv.y, bv.z, bv.w};
#pragma unroll
            for (int i = 0; i < 4; ++i)
#pragma unroll
                for (int j = 0; j < 4; ++j) acc[i][j] += av[i] * bb[j];
        }
        __syncthreads();
    }
    for (int i = 0; i < 4; ++i) {
        int m = m0 + ty * 4 + i;
        int n = n0 + tx * 4;
        float* Cp = C + (size_t)m * CD + n;
        if (n + 3 < CD) {
            float4 v = {acc[i][0], acc[i][1], acc[i][2], acc[i][3]};
            *reinterpret_cast<float4*>(Cp) = v;
        } else {
            for (int j = 0; j < 4; ++j) if (n + j < CD) Cp[j] = acc[i][j];
        }
    }
}

// ---------- s1[r] = leaky(c0 + X4[r,:]·a[300:600]), p[r] = X4[r,:]·a2[0:300] ----------
__global__ void k_score(const float* __restrict__ X4, const float* __restrict__ a,
                        const float* __restrict__ a2, const float* __restrict__ wc,
                        float alpha, float* __restrict__ s1, float* __restrict__ p, int M) {
    int gw = (blockIdx.x * blockDim.x + threadIdx.x) >> 6;
    int lane = threadIdx.x & 63;
    if (gw >= M) return;
    const float* row = X4 + (size_t)gw * CD;
    float d1 = 0.f, d2 = 0.f, dc = 0.f;
    for (int d = lane; d < CD; d += 64) {
        float x = row[d];
        d1 += x * a[CD + d];
        d2 += x * a2[d];
        dc += wc[d] * a[d];
    }
    for (int o = 32; o; o >>= 1) {
        d1 += __shfl_down(d1, o);
        d2 += __shfl_down(d2, o);
        dc += __shfl_down(dc, o);
    }
    if (lane == 0) {
        float v = dc + d1;
        s1[gw] = v > 0.f ? v : alpha * v;
        p[gw] = d2;
    }
}

// ---------- per-batch max over s1, e1 = exp(s1 - max) ----------
__global__ __launch_bounds__(1024) void k_bmax(const float* __restrict__ s1,
                                               float* __restrict__ e1) {
    __shared__ float red[16];
    int b = blockIdx.x, t = threadIdx.x;
    float v = s1[b * CN + t];
    float m = v;
    for (int o = 32; o; o >>= 1) m = fmaxf(m, __shfl_xor(m, o));
    if ((t & 63) == 0) red[t >> 6] = m;
    __syncthreads();
    if (t == 0) {
        float mm = red[0];
        for (int i = 1; i < 16; ++i) mm = fmaxf(mm, red[i]);
        red[0] = mm;
    }
    __syncthreads();
    e1[b * CN + t] = __expf(v - red[0]);
}

// ---------- denom[b,e] = sum_n HT[b,e,n]*e1[b,n] ----------
__global__ void k_denom(const int* __restrict__ HT, const float* __restrict__ e1,
                        float* __restrict__ denom) {
    int gw = (blockIdx.x * blockDim.x + threadIdx.x) >> 6;   // b*E+e
    int lane = threadIdx.x & 63;
    if (gw >= CB * CE) return;
    int b = gw >> 9;
    const int* row = HT + (size_t)gw * CN;
    const float* ev = e1 + b * CN;
    float s = 0.f;
    for (int n = lane; n < CN; n += 64)
        s += row[n] ? ev[n] : 0.f;
    for (int o = 32; o; o >>= 1) s += __shfl_down(s, o);
    if (lane == 0) denom[gw] = s;
}

// ---------- edge[b,e,d] = (sum_k HT[b,e,k]*e1[b,k]*Xs[b,k,d]) / denom[b,e] ----------
__global__ __launch_bounds__(256) void k_edge_gemm(const int* __restrict__ HT,
        const float* __restrict__ e1, const float* __restrict__ Xs,
        const float* __restrict__ denom, float* __restrict__ edge) {
    __shared__ float As[64][20];
    __shared__ float Ws[16][68];
    int b = blockIdx.z;
    int tid = threadIdx.x;
    int n0 = blockIdx.x * 64, e0 = blockIdx.y * 64;
    int tx = tid & 15, ty = tid >> 4;
    int la_r = tid >> 2, la_c = (tid & 3) << 2;
    int lw_r = tid >> 4, lw_c = (tid & 15) << 2;
    float acc[4][4] = {};
    const int* HTb = HT + (size_t)b * CE * CN;
    const float* e1b = e1 + b * CN;
    const float* Xb = Xs + (size_t)b * CN * CD;
    for (int k0 = 0; k0 < CN; k0 += 16) {
        {
            int kc = k0 + la_c;
            int4 hv = *reinterpret_cast<const int4*>(HTb + (size_t)(e0 + la_r) * CN + kc);
            float4 av;
            av.x = hv.x ? e1b[kc]     : 0.f;
            av.y = hv.y ? e1b[kc + 1] : 0.f;
            av.z = hv.z ? e1b[kc + 2] : 0.f;
            av.w = hv.w ? e1b[kc + 3] : 0.f;
            *reinterpret_cast<float4*>(&As[la_r][la_c]) = av;
        }
        {
            int kr = k0 + lw_r;
            float4 wv = {0.f, 0.f, 0.f, 0.f};
            const float* Wp = Xb + (size_t)kr * CD + n0 + lw_c;
            if (n0 + lw_c + 3 < CD) wv = *reinterpret_cast<const float4*>(Wp);
            else {
                if (n0 + lw_c     < CD) wv.x = Wp[0];
                if (n0 + lw_c + 1 < CD) wv.y = Wp[1];
                if (n0 + lw_c + 2 < CD) wv.z = Wp[2];
            }
            *reinterpret_cast<float4*>(&Ws[lw_r][lw_c]) = wv;
        }
        __syncthreads();
#pragma unroll
        for (int k = 0; k < 16; ++k) {
            float av[4];
#pragma unroll
            for (int i = 0; i < 4; ++i) av[i] = As[ty * 4 + i][k];
            float4 bv = *reinterpret_cast<const float4*>(&Ws[k][tx * 4]);
            float bb[4] = {bv.x, bv.y, bv.z, bv.w};
#pragma unroll
            for (int i = 0; i < 4; ++i)
#pragma unroll
                for (int j = 0; j < 4; ++j) acc[i][j] += av[i] * bb[j];
        }
        __syncthreads();
    }
    for (int i = 0; i < 4; ++i) {
        int e = e0 + ty * 4 + i;
        float den = denom[b * CE + e];
        float inv = den != 0.f ? 1.f / den : 0.f;
        int n = n0 + tx * 4;
        float* Cp = edge + ((size_t)b * CE + e) * CD + n;
        if (n + 3 < CD) {
            float4 v = {acc[i][0] * inv, acc[i][1] * inv, acc[i][2] * inv, acc[i][3] * inv};
            *reinterpret_cast<float4*>(Cp) = v;
        } else {
            for (int j = 0; j < 4; ++j) if (n + j < CD) Cp[j] = acc[i][j] * inv;
        }
    }
}

// ---------- q[r] = E4[r,:]·a2[300:600] ----------
__global__ void k_q(const float* __restrict__ E4, const float* __restrict__ a2,
                    float* __restrict__ q, int M) {
    int gw = (blockIdx.x * blockDim.x + threadIdx.x) >> 6;
    int lane = threadIdx.x & 63;
    if (gw >= M) return;
    const float* row = E4 + (size_t)gw * CD;
    float d2 = 0.f;
    for (int d = lane; d < CD; d += 64) d2 += row[d] * a2[CD + d];
    for (int o = 32; o; o >>= 1) d2 += __shfl_down(d2, o);
    if (lane == 0) q[gw] = d2;
}

// ---------- fused node attention: out[n,:] = softmax_e(leaky(p[n]+q[e]), mask) @ edge ----------
__global__ __launch_bounds__(64) void k_node_attn(const unsigned char* __restrict__ HTt,
        const float* __restrict__ p, const float* __restrict__ q,
        const float* __restrict__ edge, float alpha, int do_elu, float* __restrict__ out) {
    __shared__ float ws[8][CE];
    int blk = blockIdx.x;
    int b = blk >> 7;              // 128 blocks per batch
    int n0 = (blk & 127) << 3;     // 8 nodes per block
    int lane = threadIdx.x;
    const float* qb = q + b * CE;
    // phase 1: attention weights for 8 nodes
    for (int i = 0; i < 8; ++i) {
        int n = n0 + i;
        float pn = p[b * CN + n];
        const unsigned char* mrow = HTt + ((size_t)b * CN + n) * CE;
        float sc[8]; int mk[8];
        float mx = -3.4e38f; int cnt = 0;
#pragma unroll
        for (int j = 0; j < 8; ++j) {
            int e = lane + (j << 6);
            mk[j] = mrow[e];
            float v = pn + qb[e];
            v = v > 0.f ? v : alpha * v;
            sc[j] = v;
            if (mk[j]) { mx = fmaxf(mx, v); cnt++; }
        }
        for (int o = 32; o; o >>= 1) { mx = fmaxf(mx, __shfl_xor(mx, o)); cnt += __shfl_xor(cnt, o); }
        if (cnt > 0) {
            float sum = 0.f; float w8[8];
#pragma unroll
            for (int j = 0; j < 8; ++j) { float w = mk[j] ? __expf(sc[j] - mx) : 0.f; w8[j] = w; sum += w; }
            for (int o = 32; o; o >>= 1) sum += __shfl_xor(sum, o);
            float inv = 1.f / sum;
#pragma unroll
            for (int j = 0; j < 8; ++j) ws[i][lane + (j << 6)] = w8[j] * inv;
        } else {
            const float u = 1.f / (float)CE;   // jax: softmax over all-NEG row -> uniform
#pragma unroll
            for (int j = 0; j < 8; ++j) ws[i][lane + (j << 6)] = u;
        }
    }
    __syncthreads();
    // phase 2: out[n, :] = sum_e ws[n][e] * edge[b, e, :]
    float acc[8][5] = {};
    const float* eb = edge + (size_t)b * CE * CD;
    bool tail = lane < (CD - 256);
    for (int e = 0; e < CE; ++e) {
        const float* er = eb + (size_t)e * CD;
        float v0 = er[lane];
        float v1 = er[lane + 64];
        float v2 = er[lane + 128];
        float v3 = er[lane + 192];
        float v4 = tail ? er[lane + 256] : 0.f;
#pragma unroll
        for (int i = 0; i < 8; ++i) {
            float w = ws[i][e];
            acc[i][0] += w * v0; acc[i][1] += w * v1; acc[i][2] += w * v2;
            acc[i][3] += w * v3; acc[i][4] += w * v4;
        }
    }
    for (int i = 0; i < 8; ++i) {
        float* orow = out + ((size_t)b * CN + n0 + i) * CD;
#pragma unroll
        for (int jj = 0; jj < 5; ++jj) {
            int d = lane + (jj << 6);
            if (d < CD) {
                float v = acc[i][jj];
                if (do_elu) v = v > 0.f ? v : expm1f(v);
                orow[d] = v;
            }
        }
    }
}

extern "C" void kernel_launch(void* const* d_in, const int* in_sizes, int n_in,
                              void* d_out, int out_size, void* d_ws, size_t ws_size,
                              hipStream_t stream) {
    const int*   inputs = (const int*)d_in[0];
    const int*   HT     = (const int*)d_in[1];
    const float* emb    = (const float*)d_in[2];
    const float* w2_1   = (const float*)d_in[3];
    const float* w3_1   = (const float*)d_in[4];
    const float* a_1    = (const float*)d_in[5];
    const float* a2_1   = (const float*)d_in[6];
    const float* wc_1   = (const float*)d_in[7];
    const float* w_2    = (const float*)d_in[8];
    const float* w2_2   = (const float*)d_in[9];
    const float* w3_2   = (const float*)d_in[10];
    const float* a_2    = (const float*)d_in[11];
    const float* a2_2   = (const float*)d_in[12];
    const float* wc_2   = (const float*)d_in[13];

    char* ws = (char*)d_ws;
    float* X0           = (float*)(ws);                     // 39,321,600 B  (X0 -> X4_2 -> XW)
    float* X4           = (float*)(ws + 39321600);          // 39,321,600 B  (X4_1 -> X1)
    float* edge         = (float*)(ws + 78643200);          // 19,660,800 B
    float* e4           = (float*)(ws + 98304000);          // 19,660,800 B
    unsigned char* HTt  = (unsigned char*)(ws + 117964800); // 16,777,216 B
    float* s1           = (float*)(ws + 134742016);         // 131,072 B
    float* p            = (float*)(ws + 134873088);         // 131,072 B
    float* e1           = (float*)(ws + 135004160);         // 131,072 B
    float* qv           = (float*)(ws + 135135232);         //  65,536 B
    float* den          = (float*)(ws + 135200768);         //  65,536 B
    // total: 135,266,304 B

    k_embed<<<9600, 256, 0, stream>>>(inputs, emb, X0);
    k_transpose<<<dim3(16, 32, 32), dim3(32, 8), 0, stream>>>(HT, HTt);

    // ---- layer 1: transfer=False, concat=True (ELU), alpha=0.1 ----
    k_gemm300<<<dim3(5, 512), 256, 0, stream>>>(X0, w2_1, X4, CB * CN);
    k_score<<<CB * CN / 4, 256, 0, stream>>>(X4, a_1, a2_1, wc_1, 0.1f, s1, p, CB * CN);
    k_bmax<<<CB, 1024, 0, stream>>>(s1, e1);
    k_denom<<<4096, 256, 0, stream>>>(HT, e1, den);
    k_edge_gemm<<<dim3(5, 8, 32), 256, 0, stream>>>(HT, e1, X0, den, edge);
    k_gemm300<<<dim3(5, 256), 256, 0, stream>>>(edge, w3_1, e4, CB * CE);
    k_q<<<CB * CE / 4, 256, 0, stream>>>(e4, a2_1, qv, CB * CE);
    k_node_attn<<<4096, 64, 0, stream>>>(HTt, p, qv, edge, 0.1f, 1, X4);   // X1 -> X4 buf

    // ---- layer 2: transfer=True, concat=False, alpha=0.2 ----
    k_gemm300<<<dim3(5, 512), 256, 0, stream>>>(X4, w2_2, X0, CB * CN);    // X4_2
    k_score<<<CB * CN / 4, 256, 0, stream>>>(X0, a_2, a2_2, wc_2, 0.2f, s1, p, CB * CN);
    k_bmax<<<CB, 1024, 0, stream>>>(s1, e1);
    k_gemm300<<<dim3(5, 512), 256, 0, stream>>>(X4, w_2, X0, CB * CN);     // XW (after score read X4_2)
    k_denom<<<4096, 256, 0, stream>>>(HT, e1, den);
    k_edge_gemm<<<dim3(5, 8, 32), 256, 0, stream>>>(HT, e1, X0, den, edge);
    k_gemm300<<<dim3(5, 256), 256, 0, stream>>>(edge, w3_2, e4, CB * CE);
    k_q<<<CB * CE / 4, 256, 0, stream>>>(e4, a2_2, qv, CB * CE);
    k_node_attn<<<4096, 64, 0, stream>>>(HTt, p, qv, edge, 0.2f, 0, (float*)d_out);
}

// Round 2
// 1243.720 us; speedup vs baseline: 1.0730x; 1.0730x over previous
//
#include <hip/hip_runtime.h>
#include <hip/hip_bf16.h>

#define CB 32
#define CN 1024
#define CE 512
#define CD 300

// ---------- embedding gather: X[r,:] = emb[idx[r],:] ----------
__global__ void k_embed(const int* __restrict__ idx, const float* __restrict__ emb,
                        float* __restrict__ X) {
    int gid = blockIdx.x * blockDim.x + threadIdx.x;
    const int total = CB * CN * 75;   // 75 float4 per 300-float row
    if (gid >= total) return;
    int r = gid / 75, c = gid % 75;
    int e = idx[r];
    reinterpret_cast<float4*>(X)[(size_t)r * 75 + c] =
        reinterpret_cast<const float4*>(emb)[(size_t)e * 75 + c];
}

// ---------- transpose HT [B,E,N] int -> HTt [B,N,E] u8 ----------
__global__ void k_transpose(const int* __restrict__ HT, unsigned char* __restrict__ HTt) {
    __shared__ int tile[32][33];
    int b = blockIdx.z;
    int e0 = blockIdx.x * 32, n0 = blockIdx.y * 32;
    int tx = threadIdx.x, ty = threadIdx.y;
    for (int i = ty; i < 32; i += 8)
        tile[i][tx] = HT[((size_t)b * CE + e0 + i) * CN + n0 + tx];
    __syncthreads();
    for (int i = ty; i < 32; i += 8)
        HTt[((size_t)b * CN + n0 + i) * CE + e0 + tx] = (unsigned char)(tile[tx][i] > 0 ? 1 : 0);
}

// ---------- C[M,300] = A[M,300] @ W[300,300], M % 64 == 0 ----------
__global__ __launch_bounds__(256) void k_gemm300(const float* __restrict__ A,
                                                 const float* __restrict__ W,
                                                 float* __restrict__ C, int M) {
    __shared__ float As[64][20];
    __shared__ float Ws[16][68];
    int tid = threadIdx.x;
    int n0 = blockIdx.x * 64, m0 = blockIdx.y * 64;
    int tx = tid & 15, ty = tid >> 4;
    int la_r = tid >> 2, la_c = (tid & 3) << 2;
    int lw_r = tid >> 4, lw_c = (tid & 15) << 2;
    float acc[4][4] = {};
    for (int k0 = 0; k0 < CD; k0 += 16) {
        {   // A tile 64x16
            int kc = k0 + la_c;
            const float* Ap = A + (size_t)(m0 + la_r) * CD + kc;
            float4 av;
            if (kc + 3 < CD) av = *reinterpret_cast<const float4*>(Ap);
            else {
                av.x = kc     < CD ? Ap[0] : 0.f;
                av.y = kc + 1 < CD ? Ap[1] : 0.f;
                av.z = kc + 2 < CD ? Ap[2] : 0.f;
                av.w = 0.f;
            }
            *reinterpret_cast<float4*>(&As[la_r][la_c]) = av;
        }
        {   // W tile 16x64
            int kr = k0 + lw_r;
            float4 wv = {0.f, 0.f, 0.f, 0.f};
            if (kr < CD) {
                const float* Wp = W + (size_t)kr * CD + n0 + lw_c;
                if (n0 + lw_c + 3 < CD) wv = *reinterpret_cast<const float4*>(Wp);
                else {
                    if (n0 + lw_c     < CD) wv.x = Wp[0];
                    if (n0 + lw_c + 1 < CD) wv.y = Wp[1];
                    if (n0 + lw_c + 2 < CD) wv.z = Wp[2];
                }
            }
            *reinterpret_cast<float4*>(&Ws[lw_r][lw_c]) = wv;
        }
        __syncthreads();
#pragma unroll
        for (int k = 0; k < 16; ++k) {
            float av[4];
#pragma unroll
            for (int i = 0; i < 4; ++i) av[i] = As[ty * 4 + i][k];
            float4 bv = *reinterpret_cast<const float4*>(&Ws[k][tx * 4]);
            float bb[4] = {bv.x, bv.y, bv.z, bv.w};
#pragma unroll
            for (int i = 0; i < 4; ++i)
#pragma unroll
                for (int j = 0; j < 4; ++j) acc[i][j] += av[i] * bb[j];
        }
        __syncthreads();
    }
    for (int i = 0; i < 4; ++i) {
        int m = m0 + ty * 4 + i;
        int n = n0 + tx * 4;
        float* Cp = C + (size_t)m * CD + n;
        if (n + 3 < CD) {
            float4 v = {acc[i][0], acc[i][1], acc[i][2], acc[i][3]};
            *reinterpret_cast<float4*>(Cp) = v;
        } else {
            for (int j = 0; j < 4; ++j) if (n + j < CD) Cp[j] = acc[i][j];
        }
    }
}

// ---------- s1[r] = leaky(c0 + X4[r,:]·a[300:600]), p[r] = X4[r,:]·a2[0:300] ----------
__global__ void k_score(const float* __restrict__ X4, const float* __restrict__ a,
                        const float* __restrict__ a2, const float* __restrict__ wc,
                        float alpha, float* __restrict__ s1, float* __restrict__ p, int M) {
    int gw = (blockIdx.x * blockDim.x + threadIdx.x) >> 6;
    int lane = threadIdx.x & 63;
    if (gw >= M) return;
    const float* row = X4 + (size_t)gw * CD;
    float d1 = 0.f, d2 = 0.f, dc = 0.f;
    for (int d = lane; d < CD; d += 64) {
        float x = row[d];
        d1 += x * a[CD + d];
        d2 += x * a2[d];
        dc += wc[d] * a[d];
    }
    for (int o = 32; o; o >>= 1) {
        d1 += __shfl_down(d1, o);
        d2 += __shfl_down(d2, o);
        dc += __shfl_down(dc, o);
    }
    if (lane == 0) {
        float v = dc + d1;
        s1[gw] = v > 0.f ? v : alpha * v;
        p[gw] = d2;
    }
}

// ---------- per-batch max over s1, e1 = exp(s1 - max) ----------
__global__ __launch_bounds__(1024) void k_bmax(const float* __restrict__ s1,
                                               float* __restrict__ e1) {
    __shared__ float red[16];
    int b = blockIdx.x, t = threadIdx.x;
    float v = s1[b * CN + t];
    float m = v;
    for (int o = 32; o; o >>= 1) m = fmaxf(m, __shfl_xor(m, o));
    if ((t & 63) == 0) red[t >> 6] = m;
    __syncthreads();
    if (t == 0) {
        float mm = red[0];
        for (int i = 1; i < 16; ++i) mm = fmaxf(mm, red[i]);
        red[0] = mm;
    }
    __syncthreads();
    e1[b * CN + t] = __expf(v - red[0]);
}

// ---------- denom[b,e] = sum_n HT[b,e,n]*e1[b,n] ----------
__global__ void k_denom(const int* __restrict__ HT, const float* __restrict__ e1,
                        float* __restrict__ denom) {
    int gw = (blockIdx.x * blockDim.x + threadIdx.x) >> 6;   // b*E+e
    int lane = threadIdx.x & 63;
    if (gw >= CB * CE) return;
    int b = gw >> 9;
    const int* row = HT + (size_t)gw * CN;
    const float* ev = e1 + b * CN;
    float s = 0.f;
    for (int n = lane; n < CN; n += 64)
        s += row[n] ? ev[n] : 0.f;
    for (int o = 32; o; o >>= 1) s += __shfl_down(s, o);
    if (lane == 0) denom[gw] = s;
}

// ---------- edge[b,e,d] = (sum_k HT[b,e,k]*e1[b,k]*Xs[b,k,d]) / denom[b,e] ----------
__global__ __launch_bounds__(256) void k_edge_gemm(const int* __restrict__ HT,
        const float* __restrict__ e1, const float* __restrict__ Xs,
        const float* __restrict__ denom, float* __restrict__ edge) {
    __shared__ float As[64][20];
    __shared__ float Ws[16][68];
    int b = blockIdx.z;
    int tid = threadIdx.x;
    int n0 = blockIdx.x * 64, e0 = blockIdx.y * 64;
    int tx = tid & 15, ty = tid >> 4;
    int la_r = tid >> 2, la_c = (tid & 3) << 2;
    int lw_r = tid >> 4, lw_c = (tid & 15) << 2;
    float acc[4][4] = {};
    const int* HTb = HT + (size_t)b * CE * CN;
    const float* e1b = e1 + b * CN;
    const float* Xb = Xs + (size_t)b * CN * CD;
    for (int k0 = 0; k0 < CN; k0 += 16) {
        {
            int kc = k0 + la_c;
            int4 hv = *reinterpret_cast<const int4*>(HTb + (size_t)(e0 + la_r) * CN + kc);
            float4 av;
            av.x = hv.x ? e1b[kc]     : 0.f;
            av.y = hv.y ? e1b[kc + 1] : 0.f;
            av.z = hv.z ? e1b[kc + 2] : 0.f;
            av.w = hv.w ? e1b[kc + 3] : 0.f;
            *reinterpret_cast<float4*>(&As[la_r][la_c]) = av;
        }
        {
            int kr = k0 + lw_r;
            float4 wv = {0.f, 0.f, 0.f, 0.f};
            const float* Wp = Xb + (size_t)kr * CD + n0 + lw_c;
            if (n0 + lw_c + 3 < CD) wv = *reinterpret_cast<const float4*>(Wp);
            else {
                if (n0 + lw_c     < CD) wv.x = Wp[0];
                if (n0 + lw_c + 1 < CD) wv.y = Wp[1];
                if (n0 + lw_c + 2 < CD) wv.z = Wp[2];
            }
            *reinterpret_cast<float4*>(&Ws[lw_r][lw_c]) = wv;
        }
        __syncthreads();
#pragma unroll
        for (int k = 0; k < 16; ++k) {
            float av[4];
#pragma unroll
            for (int i = 0; i < 4; ++i) av[i] = As[ty * 4 + i][k];
            float4 bv = *reinterpret_cast<const float4*>(&Ws[k][tx * 4]);
            float bb[4] = {bv.x, bv.y, bv.z, bv.w};
#pragma unroll
            for (int i = 0; i < 4; ++i)
#pragma unroll
                for (int j = 0; j < 4; ++j) acc[i][j] += av[i] * bb[j];
        }
        __syncthreads();
    }
    for (int i = 0; i < 4; ++i) {
        int e = e0 + ty * 4 + i;
        float den = denom[b * CE + e];
        float inv = den != 0.f ? 1.f / den : 0.f;
        int n = n0 + tx * 4;
        float* Cp = edge + ((size_t)b * CE + e) * CD + n;
        if (n + 3 < CD) {
            float4 v = {acc[i][0] * inv, acc[i][1] * inv, acc[i][2] * inv, acc[i][3] * inv};
            *reinterpret_cast<float4*>(Cp) = v;
        } else {
            for (int j = 0; j < 4; ++j) if (n + j < CD) Cp[j] = acc[i][j] * inv;
        }
    }
}

// ---------- q[r] = E4[r,:]·a2[300:600] ----------
__global__ void k_q(const float* __restrict__ E4, const float* __restrict__ a2,
                    float* __restrict__ q, int M) {
    int gw = (blockIdx.x * blockDim.x + threadIdx.x) >> 6;
    int lane = threadIdx.x & 63;
    if (gw >= M) return;
    const float* row = E4 + (size_t)gw * CD;
    float d2 = 0.f;
    for (int d = lane; d < CD; d += 64) d2 += row[d] * a2[CD + d];
    for (int o = 32; o; o >>= 1) d2 += __shfl_down(d2, o);
    if (lane == 0) q[gw] = d2;
}

// ---------- fused node attention v2 ----------
// Block: 320 threads (5 waves), 16 nodes. Phase 1: waves 0-3 compute 4 nodes each
// (in parallel across nodes -> one ds_write_b128 per 64-edge chunk). Phase 2:
// thread = output dim (300/320 active), per edge: 1 coalesced L2 load +
// 4 broadcast ds_read_b128 + 16 FMA.
__global__ __launch_bounds__(320) void k_node_attn(const unsigned char* __restrict__ HTt,
        const float* __restrict__ p, const float* __restrict__ q,
        const float* __restrict__ edge, float alpha, int do_elu, float* __restrict__ out) {
    __shared__ float4 wsT[CE][4];   // [edge][node-group], group slot XOR-swizzled by (e&3)
    int blk = blockIdx.x;
    int b = blk >> 6;              // 64 blocks per batch
    int n0 = (blk & 63) << 4;      // 16 nodes per block
    int tid = threadIdx.x;
    int wv = tid >> 6, lane = tid & 63;
    const float* qb = q + b * CE;

    if (wv < 4) {
        float pn[4]; const unsigned char* mr[4];
#pragma unroll
        for (int k = 0; k < 4; ++k) {
            int n = n0 + 4 * wv + k;
            pn[k] = p[b * CN + n];
            mr[k] = HTt + ((size_t)b * CN + n) * CE;
        }
        float sc[4][8];
        int cnt[4] = {0, 0, 0, 0};
        float mx[4] = {-3.4e38f, -3.4e38f, -3.4e38f, -3.4e38f};
#pragma unroll
        for (int j = 0; j < 8; ++j) {
            int e = lane + (j << 6);
            float qe = qb[e];
#pragma unroll
            for (int k = 0; k < 4; ++k) {
                int m = mr[k][e];
                float v = pn[k] + qe;
                v = v > 0.f ? v : alpha * v;
                v = m ? v : -3.0e38f;   // masked -> effectively -inf (exp underflows to 0)
                cnt[k] += m;
                mx[k] = fmaxf(mx[k], v);
                sc[k][j] = v;
            }
        }
#pragma unroll
        for (int k = 0; k < 4; ++k) {
            for (int o = 32; o; o >>= 1) {
                mx[k] = fmaxf(mx[k], __shfl_xor(mx[k], o));
                cnt[k] += __shfl_xor(cnt[k], o);
            }
        }
        float scale[4];
#pragma unroll
        for (int k = 0; k < 4; ++k) {
            float s = 0.f;
#pragma unroll
            for (int j = 0; j < 8; ++j) { float w8 = __expf(sc[k][j] - mx[k]); sc[k][j] = w8; s += w8; }
            for (int o = 32; o; o >>= 1) s += __shfl_xor(s, o);
            if (cnt[k] > 0) scale[k] = 1.f / s;
            else {
                scale[k] = 1.f;   // jax: softmax over all-NEG row -> uniform
#pragma unroll
                for (int j = 0; j < 8; ++j) sc[k][j] = 1.f / (float)CE;
            }
        }
#pragma unroll
        for (int j = 0; j < 8; ++j) {
            int e = lane + (j << 6);
            float4 v4 = {sc[0][j] * scale[0], sc[1][j] * scale[1],
                         sc[2][j] * scale[2], sc[3][j] * scale[3]};
            wsT[e][wv ^ (e & 3)] = v4;
        }
    }
    __syncthreads();

    // phase 2: out[n0+i, d] = sum_e wsT[e][i] * edge[b,e,d]
    int d = tid;
    bool act = d < CD;
    const float* eb = edge + (size_t)b * CE * CD;
    float acc[16] = {};
#pragma unroll 4
    for (int e = 0; e < CE; ++e) {
        float v = act ? eb[(size_t)e * CD + d] : 0.f;
#pragma unroll
        for (int g = 0; g < 4; ++g) {
            float4 w4 = wsT[e][g ^ (e & 3)];
            acc[4 * g + 0] += w4.x * v;
            acc[4 * g + 1] += w4.y * v;
            acc[4 * g + 2] += w4.z * v;
            acc[4 * g + 3] += w4.w * v;
        }
    }
    if (act) {
#pragma unroll
        for (int i = 0; i < 16; ++i) {
            float o = acc[i];
            if (do_elu) o = o > 0.f ? o : expm1f(o);
            out[((size_t)b * CN + n0 + i) * CD + d] = o;
        }
    }
}

extern "C" void kernel_launch(void* const* d_in, const int* in_sizes, int n_in,
                              void* d_out, int out_size, void* d_ws, size_t ws_size,
                              hipStream_t stream) {
    const int*   inputs = (const int*)d_in[0];
    const int*   HT     = (const int*)d_in[1];
    const float* emb    = (const float*)d_in[2];
    const float* w2_1   = (const float*)d_in[3];
    const float* w3_1   = (const float*)d_in[4];
    const float* a_1    = (const float*)d_in[5];
    const float* a2_1   = (const float*)d_in[6];
    const float* wc_1   = (const float*)d_in[7];
    const float* w_2    = (const float*)d_in[8];
    const float* w2_2   = (const float*)d_in[9];
    const float* w3_2   = (const float*)d_in[10];
    const float* a_2    = (const float*)d_in[11];
    const float* a2_2   = (const float*)d_in[12];
    const float* wc_2   = (const float*)d_in[13];

    char* ws = (char*)d_ws;
    float* X0           = (float*)(ws);                     // 39,321,600 B  (X0 -> X4_2 -> XW)
    float* X4           = (float*)(ws + 39321600);          // 39,321,600 B  (X4_1 -> X1)
    float* edge         = (float*)(ws + 78643200);          // 19,660,800 B
    float* e4           = (float*)(ws + 98304000);          // 19,660,800 B
    unsigned char* HTt  = (unsigned char*)(ws + 117964800); // 16,777,216 B
    float* s1           = (float*)(ws + 134742016);         // 131,072 B
    float* p            = (float*)(ws + 134873088);         // 131,072 B
    float* e1           = (float*)(ws + 135004160);         // 131,072 B
    float* qv           = (float*)(ws + 135135232);         //  65,536 B
    float* den          = (float*)(ws + 135200768);         //  65,536 B
    // total: 135,266,304 B

    k_embed<<<9600, 256, 0, stream>>>(inputs, emb, X0);
    k_transpose<<<dim3(16, 32, 32), dim3(32, 8), 0, stream>>>(HT, HTt);

    // ---- layer 1: transfer=False, concat=True (ELU), alpha=0.1 ----
    k_gemm300<<<dim3(5, 512), 256, 0, stream>>>(X0, w2_1, X4, CB * CN);
    k_score<<<CB * CN / 4, 256, 0, stream>>>(X4, a_1, a2_1, wc_1, 0.1f, s1, p, CB * CN);
    k_bmax<<<CB, 1024, 0, stream>>>(s1, e1);
    k_denom<<<4096, 256, 0, stream>>>(HT, e1, den);
    k_edge_gemm<<<dim3(5, 8, 32), 256, 0, stream>>>(HT, e1, X0, den, edge);
    k_gemm300<<<dim3(5, 256), 256, 0, stream>>>(edge, w3_1, e4, CB * CE);
    k_q<<<CB * CE / 4, 256, 0, stream>>>(e4, a2_1, qv, CB * CE);
    k_node_attn<<<2048, 320, 0, stream>>>(HTt, p, qv, edge, 0.1f, 1, X4);   // X1 -> X4 buf

    // ---- layer 2: transfer=True, concat=False, alpha=0.2 ----
    k_gemm300<<<dim3(5, 512), 256, 0, stream>>>(X4, w2_2, X0, CB * CN);    // X4_2
    k_score<<<CB * CN / 4, 256, 0, stream>>>(X0, a_2, a2_2, wc_2, 0.2f, s1, p, CB * CN);
    k_bmax<<<CB, 1024, 0, stream>>>(s1, e1);
    k_gemm300<<<dim3(5, 512), 256, 0, stream>>>(X4, w_2, X0, CB * CN);     // XW (after score read X4_2)
    k_denom<<<4096, 256, 0, stream>>>(HT, e1, den);
    k_edge_gemm<<<dim3(5, 8, 32), 256, 0, stream>>>(HT, e1, X0, den, edge);
    k_gemm300<<<dim3(5, 256), 256, 0, stream>>>(edge, w3_2, e4, CB * CE);
    k_q<<<CB * CE / 4, 256, 0, stream>>>(e4, a2_2, qv, CB * CE);
    k_node_attn<<<2048, 320, 0, stream>>>(HTt, p, qv, edge, 0.2f, 0, (float*)d_out);
}

// Round 3
// 1073.427 us; speedup vs baseline: 1.2432x; 1.1586x over previous
//
#include <hip/hip_runtime.h>
#include <hip/hip_bf16.h>

#define CB 32
#define CN 1024
#define CE 512
#define CD 300
#define EP 320   // padded edge-row stride (floats); pad cols [300,320) are written 0

// ---------- embedding gather: X[r,:] = emb[idx[r],:] ----------
__global__ void k_embed(const int* __restrict__ idx, const float* __restrict__ emb,
                        float* __restrict__ X) {
    int gid = blockIdx.x * blockDim.x + threadIdx.x;
    const int total = CB * CN * 75;   // 75 float4 per 300-float row
    if (gid >= total) return;
    int r = gid / 75, c = gid % 75;
    int e = idx[r];
    reinterpret_cast<float4*>(X)[(size_t)r * 75 + c] =
        reinterpret_cast<const float4*>(emb)[(size_t)e * 75 + c];
}

// ---------- transpose HT [B,E,N] int -> HTt [B,N,E] u8 ----------
__global__ void k_transpose(const int* __restrict__ HT, unsigned char* __restrict__ HTt) {
    __shared__ int tile[32][33];
    int b = blockIdx.z;
    int e0 = blockIdx.x * 32, n0 = blockIdx.y * 32;
    int tx = threadIdx.x, ty = threadIdx.y;
    for (int i = ty; i < 32; i += 8)
        tile[i][tx] = HT[((size_t)b * CE + e0 + i) * CN + n0 + tx];
    __syncthreads();
    for (int i = ty; i < 32; i += 8)
        HTt[((size_t)b * CN + n0 + i) * CE + e0 + tx] = (unsigned char)(tile[tx][i] > 0 ? 1 : 0);
}

// ---------- C[M,300] = A[M,300(lda)] @ W[300,300], M % 64 == 0 ----------
__global__ __launch_bounds__(256) void k_gemm300(const float* __restrict__ A,
                                                 const float* __restrict__ W,
                                                 float* __restrict__ C, int M,
                                                 int lda, int ldc) {
    __shared__ float As[64][20];
    __shared__ float Ws[16][68];
    int tid = threadIdx.x;
    int n0 = blockIdx.x * 64, m0 = blockIdx.y * 64;
    int tx = tid & 15, ty = tid >> 4;
    int la_r = tid >> 2, la_c = (tid & 3) << 2;
    int lw_r = tid >> 4, lw_c = (tid & 15) << 2;
    float acc[4][4] = {};
    for (int k0 = 0; k0 < CD; k0 += 16) {
        {   // A tile 64x16
            int kc = k0 + la_c;
            const float* Ap = A + (size_t)(m0 + la_r) * lda + kc;
            float4 av;
            if (kc + 3 < CD) av = *reinterpret_cast<const float4*>(Ap);
            else {
                av.x = kc     < CD ? Ap[0] : 0.f;
                av.y = kc + 1 < CD ? Ap[1] : 0.f;
                av.z = kc + 2 < CD ? Ap[2] : 0.f;
                av.w = 0.f;
            }
            *reinterpret_cast<float4*>(&As[la_r][la_c]) = av;
        }
        {   // W tile 16x64
            int kr = k0 + lw_r;
            float4 wv = {0.f, 0.f, 0.f, 0.f};
            if (kr < CD) {
                const float* Wp = W + (size_t)kr * CD + n0 + lw_c;
                if (n0 + lw_c + 3 < CD) wv = *reinterpret_cast<const float4*>(Wp);
                else {
                    if (n0 + lw_c     < CD) wv.x = Wp[0];
                    if (n0 + lw_c + 1 < CD) wv.y = Wp[1];
                    if (n0 + lw_c + 2 < CD) wv.z = Wp[2];
                }
            }
            *reinterpret_cast<float4*>(&Ws[lw_r][lw_c]) = wv;
        }
        __syncthreads();
#pragma unroll
        for (int k = 0; k < 16; ++k) {
            float av[4];
#pragma unroll
            for (int i = 0; i < 4; ++i) av[i] = As[ty * 4 + i][k];
            float4 bv = *reinterpret_cast<const float4*>(&Ws[k][tx * 4]);
            float bb[4] = {bv.x, bv.y, bv.z, bv.w};
#pragma unroll
            for (int i = 0; i < 4; ++i)
#pragma unroll
                for (int j = 0; j < 4; ++j) acc[i][j] += av[i] * bb[j];
        }
        __syncthreads();
    }
    for (int i = 0; i < 4; ++i) {
        int m = m0 + ty * 4 + i;
        int n = n0 + tx * 4;
        float* Cp = C + (size_t)m * ldc + n;
        if (n + 3 < CD) {
            float4 v = {acc[i][0], acc[i][1], acc[i][2], acc[i][3]};
            *reinterpret_cast<float4*>(Cp) = v;
        } else {
            for (int j = 0; j < 4; ++j) if (n + j < CD) Cp[j] = acc[i][j];
        }
    }
}

// ---------- s1[r] = leaky(c0 + X4[r,:]·a[300:600]), p[r] = X4[r,:]·a2[0:300] ----------
__global__ void k_score(const float* __restrict__ X4, const float* __restrict__ a,
                        const float* __restrict__ a2, const float* __restrict__ wc,
                        float alpha, float* __restrict__ s1, float* __restrict__ p, int M) {
    int gw = (blockIdx.x * blockDim.x + threadIdx.x) >> 6;
    int lane = threadIdx.x & 63;
    if (gw >= M) return;
    const float* row = X4 + (size_t)gw * CD;
    float d1 = 0.f, d2 = 0.f, dc = 0.f;
    for (int d = lane; d < CD; d += 64) {
        float x = row[d];
        d1 += x * a[CD + d];
        d2 += x * a2[d];
        dc += wc[d] * a[d];
    }
    for (int o = 32; o; o >>= 1) {
        d1 += __shfl_down(d1, o);
        d2 += __shfl_down(d2, o);
        dc += __shfl_down(dc, o);
    }
    if (lane == 0) {
        float v = dc + d1;
        s1[gw] = v > 0.f ? v : alpha * v;
        p[gw] = d2;
    }
}

// ---------- per-batch max over s1, e1 = exp(s1 - max) ----------
__global__ __launch_bounds__(1024) void k_bmax(const float* __restrict__ s1,
                                               float* __restrict__ e1) {
    __shared__ float red[16];
    int b = blockIdx.x, t = threadIdx.x;
    float v = s1[b * CN + t];
    float m = v;
    for (int o = 32; o; o >>= 1) m = fmaxf(m, __shfl_xor(m, o));
    if ((t & 63) == 0) red[t >> 6] = m;
    __syncthreads();
    if (t == 0) {
        float mm = red[0];
        for (int i = 1; i < 16; ++i) mm = fmaxf(mm, red[i]);
        red[0] = mm;
    }
    __syncthreads();
    e1[b * CN + t] = __expf(v - red[0]);
}

// ---------- denom[b,e] = sum_n HT[b,e,n]*e1[b,n] ----------
__global__ void k_denom(const int* __restrict__ HT, const float* __restrict__ e1,
                        float* __restrict__ denom) {
    int gw = (blockIdx.x * blockDim.x + threadIdx.x) >> 6;   // b*E+e
    int lane = threadIdx.x & 63;
    if (gw >= CB * CE) return;
    int b = gw >> 9;
    const int* row = HT + (size_t)gw * CN;
    const float* ev = e1 + b * CN;
    float s = 0.f;
    for (int n = lane; n < CN; n += 64)
        s += row[n] ? ev[n] : 0.f;
    for (int o = 32; o; o >>= 1) s += __shfl_down(s, o);
    if (lane == 0) denom[gw] = s;
}

// ---------- edge[b,e,d] = (sum_k HT[b,e,k]*e1[b,k]*Xs[b,k,d]) / denom[b,e] ----------
// writes full EP=320-wide rows; cols >= 300 get zeros.
__global__ __launch_bounds__(256) void k_edge_gemm(const int* __restrict__ HT,
        const float* __restrict__ e1, const float* __restrict__ Xs,
        const float* __restrict__ denom, float* __restrict__ edge) {
    __shared__ float As[64][20];
    __shared__ float Ws[16][68];
    int b = blockIdx.z;
    int tid = threadIdx.x;
    int n0 = blockIdx.x * 64, e0 = blockIdx.y * 64;
    int tx = tid & 15, ty = tid >> 4;
    int la_r = tid >> 2, la_c = (tid & 3) << 2;
    int lw_r = tid >> 4, lw_c = (tid & 15) << 2;
    float acc[4][4] = {};
    const int* HTb = HT + (size_t)b * CE * CN;
    const float* e1b = e1 + b * CN;
    const float* Xb = Xs + (size_t)b * CN * CD;
    for (int k0 = 0; k0 < CN; k0 += 16) {
        {
            int kc = k0 + la_c;
            int4 hv = *reinterpret_cast<const int4*>(HTb + (size_t)(e0 + la_r) * CN + kc);
            float4 av;
            av.x = hv.x ? e1b[kc]     : 0.f;
            av.y = hv.y ? e1b[kc + 1] : 0.f;
            av.z = hv.z ? e1b[kc + 2] : 0.f;
            av.w = hv.w ? e1b[kc + 3] : 0.f;
            *reinterpret_cast<float4*>(&As[la_r][la_c]) = av;
        }
        {
            int kr = k0 + lw_r;
            float4 wv = {0.f, 0.f, 0.f, 0.f};
            const float* Wp = Xb + (size_t)kr * CD + n0 + lw_c;
            if (n0 + lw_c + 3 < CD) wv = *reinterpret_cast<const float4*>(Wp);
            else {
                if (n0 + lw_c     < CD) wv.x = Wp[0];
                if (n0 + lw_c + 1 < CD) wv.y = Wp[1];
                if (n0 + lw_c + 2 < CD) wv.z = Wp[2];
            }
            *reinterpret_cast<float4*>(&Ws[lw_r][lw_c]) = wv;
        }
        __syncthreads();
#pragma unroll
        for (int k = 0; k < 16; ++k) {
            float av[4];
#pragma unroll
            for (int i = 0; i < 4; ++i) av[i] = As[ty * 4 + i][k];
            float4 bv = *reinterpret_cast<const float4*>(&Ws[k][tx * 4]);
            float bb[4] = {bv.x, bv.y, bv.z, bv.w};
#pragma unroll
            for (int i = 0; i < 4; ++i)
#pragma unroll
                for (int j = 0; j < 4; ++j) acc[i][j] += av[i] * bb[j];
        }
        __syncthreads();
    }
    for (int i = 0; i < 4; ++i) {
        int e = e0 + ty * 4 + i;
        float den = denom[b * CE + e];
        float inv = den != 0.f ? 1.f / den : 0.f;
        int n = n0 + tx * 4;   // n0 in {0,64,128,192,256}: n<=316, always in EP bounds
        float4 v = {acc[i][0] * inv, acc[i][1] * inv, acc[i][2] * inv, acc[i][3] * inv};
        *reinterpret_cast<float4*>(edge + ((size_t)b * CE + e) * EP + n) = v;
    }
}

// ---------- q[r] = E4[r,:]·a2[300:600] ----------
__global__ void k_q(const float* __restrict__ E4, const float* __restrict__ a2,
                    float* __restrict__ q, int M) {
    int gw = (blockIdx.x * blockDim.x + threadIdx.x) >> 6;
    int lane = threadIdx.x & 63;
    if (gw >= M) return;
    const float* row = E4 + (size_t)gw * CD;
    float d2 = 0.f;
    for (int d = lane; d < CD; d += 64) d2 += row[d] * a2[CD + d];
    for (int o = 32; o; o >>= 1) d2 += __shfl_down(d2, o);
    if (lane == 0) q[gw] = d2;
}

// ---------- fused node attention v3: sparse union iteration + float4 edge loads ----
// Block 320 thr, 16 nodes (4 groups x 4 nodes). Phase 1: wave g computes softmax
// weights of its 4 nodes into wsT + ballot-compacts the union edge list of the
// group (~176 of 512 edges at 10% density). Phase 2: thread=(group, 4 dims);
// per union edge: 1 float4 load + 1 broadcast ds_read_b128 + 16 FMA.
#define ACC16(vv, ww) do { \
    acc[0][0] += (ww).x * (vv).x; acc[0][1] += (ww).x * (vv).y; \
    acc[0][2] += (ww).x * (vv).z; acc[0][3] += (ww).x * (vv).w; \
    acc[1][0] += (ww).y * (vv).x; acc[1][1] += (ww).y * (vv).y; \
    acc[1][2] += (ww).y * (vv).z; acc[1][3] += (ww).y * (vv).w; \
    acc[2][0] += (ww).z * (vv).x; acc[2][1] += (ww).z * (vv).y; \
    acc[2][2] += (ww).z * (vv).z; acc[2][3] += (ww).z * (vv).w; \
    acc[3][0] += (ww).w * (vv).x; acc[3][1] += (ww).w * (vv).y; \
    acc[3][2] += (ww).w * (vv).z; acc[3][3] += (ww).w * (vv).w; \
} while (0)

__global__ __launch_bounds__(320) void k_node_attn(const unsigned char* __restrict__ HTt,
        const float* __restrict__ p, const float* __restrict__ q,
        const float* __restrict__ edge, float alpha, int do_elu, float* __restrict__ out) {
    __shared__ float4 wsT[CE][4];   // [edge][group-slot], slot XOR-swizzled by (e&3)
    __shared__ int ulist[4][256];   // per-group union edge list (cap 256 >> mean 176+)
    __shared__ int ucnt_s[4];
    __shared__ int flag_s[4];       // any node in group with zero degree -> dense path
    int blk = blockIdx.x;
    int b = blk >> 6;              // 64 blocks per batch
    int n0 = (blk & 63) << 4;      // 16 nodes per block
    int tid = threadIdx.x;
    int wv = tid >> 6, lane = tid & 63;
    const float* qb = q + b * CE;

    if (wv < 4) {
        float pn[4]; const unsigned char* mr[4];
#pragma unroll
        for (int k = 0; k < 4; ++k) {
            int n = n0 + 4 * wv + k;
            pn[k] = p[b * CN + n];
            mr[k] = HTt + ((size_t)b * CN + n) * CE;
        }
        float sc[4][8];
        int cnt[4] = {0, 0, 0, 0};
        float mx[4] = {-3.4e38f, -3.4e38f, -3.4e38f, -3.4e38f};
        int ubits = 0;
#pragma unroll
        for (int j = 0; j < 8; ++j) {
            int e = lane + (j << 6);
            float qe = qb[e];
            int many = 0;
#pragma unroll
            for (int k = 0; k < 4; ++k) {
                int m = mr[k][e];
                float v = pn[k] + qe;
                v = v > 0.f ? v : alpha * v;
                v = m ? v : -3.0e38f;   // masked -> effectively -inf (exp underflows to 0)
                cnt[k] += m;
                many |= m;
                mx[k] = fmaxf(mx[k], v);
                sc[k][j] = v;
            }
            ubits |= (many ? 1 : 0) << j;
        }
#pragma unroll
        for (int k = 0; k < 4; ++k) {
            for (int o = 32; o; o >>= 1) {
                mx[k] = fmaxf(mx[k], __shfl_xor(mx[k], o));
                cnt[k] += __shfl_xor(cnt[k], o);
            }
        }
        float scale[4];
#pragma unroll
        for (int k = 0; k < 4; ++k) {
            float s = 0.f;
#pragma unroll
            for (int j = 0; j < 8; ++j) { float w8 = __expf(sc[k][j] - mx[k]); sc[k][j] = w8; s += w8; }
            for (int o = 32; o; o >>= 1) s += __shfl_xor(s, o);
            if (cnt[k] > 0) scale[k] = 1.f / s;
            else {
                scale[k] = 1.f;   // jax: softmax over all-NEG row -> uniform
#pragma unroll
                for (int j = 0; j < 8; ++j) sc[k][j] = 1.f / (float)CE;
            }
        }
#pragma unroll
        for (int j = 0; j < 8; ++j) {
            int e = lane + (j << 6);
            float4 v4 = {sc[0][j] * scale[0], sc[1][j] * scale[1],
                         sc[2][j] * scale[2], sc[3][j] * scale[3]};
            wsT[e][wv ^ (e & 3)] = v4;
        }
        // union list build (order-preserving ballot compaction)
        int base = 0;
        unsigned long long lmask = (1ull << lane) - 1ull;
#pragma unroll
        for (int j = 0; j < 8; ++j) {
            unsigned long long bal = __ballot((ubits >> j) & 1);
            if ((ubits >> j) & 1) {
                int off = base + (int)__popcll(bal & lmask);
                if (off < 256) ulist[wv][off] = lane + (j << 6);
            }
            base += (int)__popcll(bal);
        }
        if (lane == 0) {
            ucnt_s[wv] = base < 256 ? base : 256;
            flag_s[wv] = (cnt[0] == 0) | (cnt[1] == 0) | (cnt[2] == 0) | (cnt[3] == 0);
        }
    }
    __syncthreads();

    // phase 2: out[n0+4*grp+ni, 4*j4+di] = sum_e w * edge[b,e,:]
    int grp = tid / 80;
    int j4 = tid - grp * 80;
    const float4* eb4 = reinterpret_cast<const float4*>(edge + (size_t)b * CE * EP) + j4;
    int cnt = ucnt_s[grp];
    int dense = flag_s[grp];
    float acc[4][4] = {};
    if (!dense) {
        int i = 0;
        for (; i + 4 <= cnt; i += 4) {
            int e0 = ulist[grp][i], e1 = ulist[grp][i + 1];
            int e2 = ulist[grp][i + 2], e3 = ulist[grp][i + 3];
            float4 v0 = eb4[(size_t)e0 * 80], v1 = eb4[(size_t)e1 * 80];
            float4 v2 = eb4[(size_t)e2 * 80], v3 = eb4[(size_t)e3 * 80];
            float4 w0 = wsT[e0][grp ^ (e0 & 3)], w1 = wsT[e1][grp ^ (e1 & 3)];
            float4 w2 = wsT[e2][grp ^ (e2 & 3)], w3 = wsT[e3][grp ^ (e3 & 3)];
            ACC16(v0, w0); ACC16(v1, w1); ACC16(v2, w2); ACC16(v3, w3);
        }
        for (; i < cnt; ++i) {
            int e = ulist[grp][i];
            float4 v = eb4[(size_t)e * 80];
            float4 w = wsT[e][grp ^ (e & 3)];
            ACC16(v, w);
        }
    } else {   // degenerate zero-degree node in group (P~1e-23): full dense pass
        for (int e = 0; e < CE; ++e) {
            float4 v = eb4[(size_t)e * 80];
            float4 w = wsT[e][grp ^ (e & 3)];
            ACC16(v, w);
        }
    }
    if (j4 < 75) {
#pragma unroll
        for (int ni = 0; ni < 4; ++ni) {
            float4 o = {acc[ni][0], acc[ni][1], acc[ni][2], acc[ni][3]};
            if (do_elu) {
                o.x = o.x > 0.f ? o.x : expm1f(o.x);
                o.y = o.y > 0.f ? o.y : expm1f(o.y);
                o.z = o.z > 0.f ? o.z : expm1f(o.z);
                o.w = o.w > 0.f ? o.w : expm1f(o.w);
            }
            *reinterpret_cast<float4*>(out + ((size_t)b * CN + n0 + grp * 4 + ni) * CD + j4 * 4) = o;
        }
    }
}

extern "C" void kernel_launch(void* const* d_in, const int* in_sizes, int n_in,
                              void* d_out, int out_size, void* d_ws, size_t ws_size,
                              hipStream_t stream) {
    const int*   inputs = (const int*)d_in[0];
    const int*   HT     = (const int*)d_in[1];
    const float* emb    = (const float*)d_in[2];
    const float* w2_1   = (const float*)d_in[3];
    const float* w3_1   = (const float*)d_in[4];
    const float* a_1    = (const float*)d_in[5];
    const float* a2_1   = (const float*)d_in[6];
    const float* wc_1   = (const float*)d_in[7];
    const float* w_2    = (const float*)d_in[8];
    const float* w2_2   = (const float*)d_in[9];
    const float* w3_2   = (const float*)d_in[10];
    const float* a_2    = (const float*)d_in[11];
    const float* a2_2   = (const float*)d_in[12];
    const float* wc_2   = (const float*)d_in[13];

    char* ws = (char*)d_ws;
    float* X0           = (float*)(ws);                     // 39,321,600 B
    float* X4           = (float*)(ws + 39321600);          // 39,321,600 B
    float* edge         = (float*)(ws + 78643200);          // 20,971,520 B (EP=320)
    float* e4           = (float*)(ws + 99614720);          // 19,660,800 B
    unsigned char* HTt  = (unsigned char*)(ws + 119275520); // 16,777,216 B
    float* s1           = (float*)(ws + 136052736);         // 131,072 B
    float* p            = (float*)(ws + 136183808);         // 131,072 B
    float* e1           = (float*)(ws + 136314880);         // 131,072 B
    float* qv           = (float*)(ws + 136445952);         //  65,536 B
    float* den          = (float*)(ws + 136511488);         //  65,536 B
    // total: 136,577,024 B

    k_embed<<<9600, 256, 0, stream>>>(inputs, emb, X0);
    k_transpose<<<dim3(16, 32, 32), dim3(32, 8), 0, stream>>>(HT, HTt);

    // ---- layer 1: transfer=False, concat=True (ELU), alpha=0.1 ----
    k_gemm300<<<dim3(5, 512), 256, 0, stream>>>(X0, w2_1, X4, CB * CN, CD, CD);
    k_score<<<CB * CN / 4, 256, 0, stream>>>(X4, a_1, a2_1, wc_1, 0.1f, s1, p, CB * CN);
    k_bmax<<<CB, 1024, 0, stream>>>(s1, e1);
    k_denom<<<4096, 256, 0, stream>>>(HT, e1, den);
    k_edge_gemm<<<dim3(5, 8, 32), 256, 0, stream>>>(HT, e1, X0, den, edge);
    k_gemm300<<<dim3(5, 256), 256, 0, stream>>>(edge, w3_1, e4, CB * CE, EP, CD);
    k_q<<<CB * CE / 4, 256, 0, stream>>>(e4, a2_1, qv, CB * CE);
    k_node_attn<<<2048, 320, 0, stream>>>(HTt, p, qv, edge, 0.1f, 1, X4);   // X1 -> X4 buf

    // ---- layer 2: transfer=True, concat=False, alpha=0.2 ----
    k_gemm300<<<dim3(5, 512), 256, 0, stream>>>(X4, w2_2, X0, CB * CN, CD, CD);  // X4_2
    k_score<<<CB * CN / 4, 256, 0, stream>>>(X0, a_2, a2_2, wc_2, 0.2f, s1, p, CB * CN);
    k_bmax<<<CB, 1024, 0, stream>>>(s1, e1);
    k_gemm300<<<dim3(5, 512), 256, 0, stream>>>(X4, w_2, X0, CB * CN, CD, CD);   // XW
    k_denom<<<4096, 256, 0, stream>>>(HT, e1, den);
    k_edge_gemm<<<dim3(5, 8, 32), 256, 0, stream>>>(HT, e1, X0, den, edge);
    k_gemm300<<<dim3(5, 256), 256, 0, stream>>>(edge, w3_2, e4, CB * CE, EP, CD);
    k_q<<<CB * CE / 4, 256, 0, stream>>>(e4, a2_2, qv, CB * CE);
    k_node_attn<<<2048, 320, 0, stream>>>(HTt, p, qv, edge, 0.2f, 0, (float*)d_out);
}

// Round 4
// 967.440 us; speedup vs baseline: 1.3794x; 1.1096x over previous
//
#include <hip/hip_runtime.h>
#include <hip/hip_bf16.h>

#define CB 32
#define CN 1024
#define CE 512
#define CD 300
#define EP 320   // padded edge-row stride (floats); pad cols [300,320) are written 0

// ---------- embedding gather: X[r,:] = emb[idx[r],:] ----------
__global__ void k_embed(const int* __restrict__ idx, const float* __restrict__ emb,
                        float* __restrict__ X) {
    int gid = blockIdx.x * blockDim.x + threadIdx.x;
    const int total = CB * CN * 75;   // 75 float4 per 300-float row
    if (gid >= total) return;
    int r = gid / 75, c = gid % 75;
    int e = idx[r];
    reinterpret_cast<float4*>(X)[(size_t)r * 75 + c] =
        reinterpret_cast<const float4*>(emb)[(size_t)e * 75 + c];
}

// ---------- transpose HT [B,E,N] int -> HTt [B,N,E] u8 ----------
__global__ void k_transpose(const int* __restrict__ HT, unsigned char* __restrict__ HTt) {
    __shared__ int tile[32][33];
    int b = blockIdx.z;
    int e0 = blockIdx.x * 32, n0 = blockIdx.y * 32;
    int tx = threadIdx.x, ty = threadIdx.y;
    for (int i = ty; i < 32; i += 8)
        tile[i][tx] = HT[((size_t)b * CE + e0 + i) * CN + n0 + tx];
    __syncthreads();
    for (int i = ty; i < 32; i += 8)
        HTt[((size_t)b * CN + n0 + i) * CE + e0 + tx] = (unsigned char)(tile[tx][i] > 0 ? 1 : 0);
}

// ---------- C[M,300] = A[M,300(lda)] @ W[300,300], M % 64 == 0 ----------
__global__ __launch_bounds__(256) void k_gemm300(const float* __restrict__ A,
                                                 const float* __restrict__ W,
                                                 float* __restrict__ C, int M,
                                                 int lda, int ldc) {
    __shared__ float As[64][20];
    __shared__ float Ws[16][68];
    int tid = threadIdx.x;
    int n0 = blockIdx.x * 64, m0 = blockIdx.y * 64;
    int tx = tid & 15, ty = tid >> 4;
    int la_r = tid >> 2, la_c = (tid & 3) << 2;
    int lw_r = tid >> 4, lw_c = (tid & 15) << 2;
    float acc[4][4] = {};
    for (int k0 = 0; k0 < CD; k0 += 16) {
        {   // A tile 64x16
            int kc = k0 + la_c;
            const float* Ap = A + (size_t)(m0 + la_r) * lda + kc;
            float4 av;
            if (kc + 3 < CD) av = *reinterpret_cast<const float4*>(Ap);
            else {
                av.x = kc     < CD ? Ap[0] : 0.f;
                av.y = kc + 1 < CD ? Ap[1] : 0.f;
                av.z = kc + 2 < CD ? Ap[2] : 0.f;
                av.w = 0.f;
            }
            *reinterpret_cast<float4*>(&As[la_r][la_c]) = av;
        }
        {   // W tile 16x64
            int kr = k0 + lw_r;
            float4 wv = {0.f, 0.f, 0.f, 0.f};
            if (kr < CD) {
                const float* Wp = W + (size_t)kr * CD + n0 + lw_c;
                if (n0 + lw_c + 3 < CD) wv = *reinterpret_cast<const float4*>(Wp);
                else {
                    if (n0 + lw_c     < CD) wv.x = Wp[0];
                    if (n0 + lw_c + 1 < CD) wv.y = Wp[1];
                    if (n0 + lw_c + 2 < CD) wv.z = Wp[2];
                }
            }
            *reinterpret_cast<float4*>(&Ws[lw_r][lw_c]) = wv;
        }
        __syncthreads();
#pragma unroll
        for (int k = 0; k < 16; ++k) {
            float av[4];
#pragma unroll
            for (int i = 0; i < 4; ++i) av[i] = As[ty * 4 + i][k];
            float4 bv = *reinterpret_cast<const float4*>(&Ws[k][tx * 4]);
            float bb[4] = {bv.x, bv.y, bv.z, bv.w};
#pragma unroll
            for (int i = 0; i < 4; ++i)
#pragma unroll
                for (int j = 0; j < 4; ++j) acc[i][j] += av[i] * bb[j];
        }
        __syncthreads();
    }
    for (int i = 0; i < 4; ++i) {
        int m = m0 + ty * 4 + i;
        int n = n0 + tx * 4;
        float* Cp = C + (size_t)m * ldc + n;
        if (n + 3 < CD) {
            float4 v = {acc[i][0], acc[i][1], acc[i][2], acc[i][3]};
            *reinterpret_cast<float4*>(Cp) = v;
        } else {
            for (int j = 0; j < 4; ++j) if (n + j < CD) Cp[j] = acc[i][j];
        }
    }
}

// ---------- s1[r] = leaky(c0 + X4[r,:]·a[300:600]), p[r] = X4[r,:]·a2[0:300] ----------
__global__ void k_score(const float* __restrict__ X4, const float* __restrict__ a,
                        const float* __restrict__ a2, const float* __restrict__ wc,
                        float alpha, float* __restrict__ s1, float* __restrict__ p, int M) {
    int gw = (blockIdx.x * blockDim.x + threadIdx.x) >> 6;
    int lane = threadIdx.x & 63;
    if (gw >= M) return;
    const float* row = X4 + (size_t)gw * CD;
    float d1 = 0.f, d2 = 0.f, dc = 0.f;
    for (int d = lane; d < CD; d += 64) {
        float x = row[d];
        d1 += x * a[CD + d];
        d2 += x * a2[d];
        dc += wc[d] * a[d];
    }
    for (int o = 32; o; o >>= 1) {
        d1 += __shfl_down(d1, o);
        d2 += __shfl_down(d2, o);
        dc += __shfl_down(dc, o);
    }
    if (lane == 0) {
        float v = dc + d1;
        s1[gw] = v > 0.f ? v : alpha * v;
        p[gw] = d2;
    }
}

// ---------- per-batch max over s1, e1 = exp(s1 - max) ----------
__global__ __launch_bounds__(1024) void k_bmax(const float* __restrict__ s1,
                                               float* __restrict__ e1) {
    __shared__ float red[16];
    int b = blockIdx.x, t = threadIdx.x;
    float v = s1[b * CN + t];
    float m = v;
    for (int o = 32; o; o >>= 1) m = fmaxf(m, __shfl_xor(m, o));
    if ((t & 63) == 0) red[t >> 6] = m;
    __syncthreads();
    if (t == 0) {
        float mm = red[0];
        for (int i = 1; i < 16; ++i) mm = fmaxf(mm, red[i]);
        red[0] = mm;
    }
    __syncthreads();
    e1[b * CN + t] = __expf(v - red[0]);
}

// ---------- sparse edge aggregation ----------
// One wave per (b,e): edge[b,e,:] = (sum_{n in e} e1[n] * Xs[b,n,:]) / (sum e1[n]).
// HT row read once; members found by ballot + ffs (wave-uniform loop, ascending n
// -> same nonzero summation order as the dense reference). Writes EP=320 rows,
// pad cols [300,320) zeroed. Replaces k_denom + dense k_edge_gemm.
__global__ __launch_bounds__(256) void k_edge_agg(const int* __restrict__ HT,
        const float* __restrict__ e1, const float* __restrict__ Xs,
        float* __restrict__ edge) {
    int gw = (blockIdx.x * blockDim.x + threadIdx.x) >> 6;   // b*CE + e
    int lane = threadIdx.x & 63;
    int b = gw >> 9;
    const int* hrow = HT + (size_t)gw * CN;
    const float* e1b = e1 + b * CN;
    const float* Xb = Xs + (size_t)b * CN * CD;
    float acc[5] = {};
    float den = 0.f;
    bool tail = lane < (CD - 256);
    int any = 0;
#pragma unroll
    for (int c = 0; c < 16; ++c) {
        int n0 = c << 6;
        int m = hrow[n0 + lane];
        float wv = e1b[n0 + lane];
        unsigned long long bal = __ballot(m != 0);
        any |= (bal != 0ull);
        while (bal) {
            int j = (int)__ffsll(bal) - 1;
            bal &= bal - 1ull;
            float w = __shfl(wv, j);
            const float* row = Xb + (size_t)(n0 + j) * CD;
            den += w;
            acc[0] += w * row[lane];
            acc[1] += w * row[lane + 64];
            acc[2] += w * row[lane + 128];
            acc[3] += w * row[lane + 192];
            if (tail) acc[4] += w * row[lane + 256];
        }
    }
    float inv = any ? 1.f / den : 0.f;   // zero-member edge (P~1e-47): zeros, as before
    float* erow = edge + (size_t)gw * EP;
    erow[lane]       = acc[0] * inv;
    erow[lane + 64]  = acc[1] * inv;
    erow[lane + 128] = acc[2] * inv;
    erow[lane + 192] = acc[3] * inv;
    erow[lane + 256] = tail ? acc[4] * inv : 0.f;   // lanes 44..63 zero the pad
}

// ---------- q[r] = E4[r,:]·a2[300:600] ----------
__global__ void k_q(const float* __restrict__ E4, const float* __restrict__ a2,
                    float* __restrict__ q, int M) {
    int gw = (blockIdx.x * blockDim.x + threadIdx.x) >> 6;
    int lane = threadIdx.x & 63;
    if (gw >= M) return;
    const float* row = E4 + (size_t)gw * CD;
    float d2 = 0.f;
    for (int d = lane; d < CD; d += 64) d2 += row[d] * a2[CD + d];
    for (int o = 32; o; o >>= 1) d2 += __shfl_down(d2, o);
    if (lane == 0) q[gw] = d2;
}

// ---------- fused node attention v3: sparse union iteration + float4 edge loads ----
#define ACC16(vv, ww) do { \
    acc[0][0] += (ww).x * (vv).x; acc[0][1] += (ww).x * (vv).y; \
    acc[0][2] += (ww).x * (vv).z; acc[0][3] += (ww).x * (vv).w; \
    acc[1][0] += (ww).y * (vv).x; acc[1][1] += (ww).y * (vv).y; \
    acc[1][2] += (ww).y * (vv).z; acc[1][3] += (ww).y * (vv).w; \
    acc[2][0] += (ww).z * (vv).x; acc[2][1] += (ww).z * (vv).y; \
    acc[2][2] += (ww).z * (vv).z; acc[2][3] += (ww).z * (vv).w; \
    acc[3][0] += (ww).w * (vv).x; acc[3][1] += (ww).w * (vv).y; \
    acc[3][2] += (ww).w * (vv).z; acc[3][3] += (ww).w * (vv).w; \
} while (0)

__global__ __launch_bounds__(320) void k_node_attn(const unsigned char* __restrict__ HTt,
        const float* __restrict__ p, const float* __restrict__ q,
        const float* __restrict__ edge, float alpha, int do_elu, float* __restrict__ out) {
    __shared__ float4 wsT[CE][4];   // [edge][group-slot], slot XOR-swizzled by (e&3)
    __shared__ int ulist[4][256];   // per-group union edge list (cap 256 >> mean 176+)
    __shared__ int ucnt_s[4];
    __shared__ int flag_s[4];       // any node in group with zero degree -> dense path
    int blk = blockIdx.x;
    int b = blk >> 6;              // 64 blocks per batch
    int n0 = (blk & 63) << 4;      // 16 nodes per block
    int tid = threadIdx.x;
    int wv = tid >> 6, lane = tid & 63;
    const float* qb = q + b * CE;

    if (wv < 4) {
        float pn[4]; const unsigned char* mr[4];
#pragma unroll
        for (int k = 0; k < 4; ++k) {
            int n = n0 + 4 * wv + k;
            pn[k] = p[b * CN + n];
            mr[k] = HTt + ((size_t)b * CN + n) * CE;
        }
        float sc[4][8];
        int cnt[4] = {0, 0, 0, 0};
        float mx[4] = {-3.4e38f, -3.4e38f, -3.4e38f, -3.4e38f};
        int ubits = 0;
#pragma unroll
        for (int j = 0; j < 8; ++j) {
            int e = lane + (j << 6);
            float qe = qb[e];
            int many = 0;
#pragma unroll
            for (int k = 0; k < 4; ++k) {
                int m = mr[k][e];
                float v = pn[k] + qe;
                v = v > 0.f ? v : alpha * v;
                v = m ? v : -3.0e38f;   // masked -> effectively -inf (exp underflows to 0)
                cnt[k] += m;
                many |= m;
                mx[k] = fmaxf(mx[k], v);
                sc[k][j] = v;
            }
            ubits |= (many ? 1 : 0) << j;
        }
#pragma unroll
        for (int k = 0; k < 4; ++k) {
            for (int o = 32; o; o >>= 1) {
                mx[k] = fmaxf(mx[k], __shfl_xor(mx[k], o));
                cnt[k] += __shfl_xor(cnt[k], o);
            }
        }
        float scale[4];
#pragma unroll
        for (int k = 0; k < 4; ++k) {
            float s = 0.f;
#pragma unroll
            for (int j = 0; j < 8; ++j) { float w8 = __expf(sc[k][j] - mx[k]); sc[k][j] = w8; s += w8; }
            for (int o = 32; o; o >>= 1) s += __shfl_xor(s, o);
            if (cnt[k] > 0) scale[k] = 1.f / s;
            else {
                scale[k] = 1.f;   // jax: softmax over all-NEG row -> uniform
#pragma unroll
                for (int j = 0; j < 8; ++j) sc[k][j] = 1.f / (float)CE;
            }
        }
#pragma unroll
        for (int j = 0; j < 8; ++j) {
            int e = lane + (j << 6);
            float4 v4 = {sc[0][j] * scale[0], sc[1][j] * scale[1],
                         sc[2][j] * scale[2], sc[3][j] * scale[3]};
            wsT[e][wv ^ (e & 3)] = v4;
        }
        // union list build (order-preserving ballot compaction)
        int base = 0;
        unsigned long long lmask = (1ull << lane) - 1ull;
#pragma unroll
        for (int j = 0; j < 8; ++j) {
            unsigned long long bal = __ballot((ubits >> j) & 1);
            if ((ubits >> j) & 1) {
                int off = base + (int)__popcll(bal & lmask);
                if (off < 256) ulist[wv][off] = lane + (j << 6);
            }
            base += (int)__popcll(bal);
        }
        if (lane == 0) {
            ucnt_s[wv] = base < 256 ? base : 256;
            flag_s[wv] = (cnt[0] == 0) | (cnt[1] == 0) | (cnt[2] == 0) | (cnt[3] == 0);
        }
    }
    __syncthreads();

    // phase 2: out[n0+4*grp+ni, 4*j4+di] = sum_e w * edge[b,e,:]
    int grp = tid / 80;
    int j4 = tid - grp * 80;
    const float4* eb4 = reinterpret_cast<const float4*>(edge + (size_t)b * CE * EP) + j4;
    int cnt = ucnt_s[grp];
    int dense = flag_s[grp];
    float acc[4][4] = {};
    if (!dense) {
        int i = 0;
        for (; i + 4 <= cnt; i += 4) {
            int e0 = ulist[grp][i], e1 = ulist[grp][i + 1];
            int e2 = ulist[grp][i + 2], e3 = ulist[grp][i + 3];
            float4 v0 = eb4[(size_t)e0 * 80], v1 = eb4[(size_t)e1 * 80];
            float4 v2 = eb4[(size_t)e2 * 80], v3 = eb4[(size_t)e3 * 80];
            float4 w0 = wsT[e0][grp ^ (e0 & 3)], w1 = wsT[e1][grp ^ (e1 & 3)];
            float4 w2 = wsT[e2][grp ^ (e2 & 3)], w3 = wsT[e3][grp ^ (e3 & 3)];
            ACC16(v0, w0); ACC16(v1, w1); ACC16(v2, w2); ACC16(v3, w3);
        }
        for (; i < cnt; ++i) {
            int e = ulist[grp][i];
            float4 v = eb4[(size_t)e * 80];
            float4 w = wsT[e][grp ^ (e & 3)];
            ACC16(v, w);
        }
    } else {   // degenerate zero-degree node in group (P~1e-23): full dense pass
        for (int e = 0; e < CE; ++e) {
            float4 v = eb4[(size_t)e * 80];
            float4 w = wsT[e][grp ^ (e & 3)];
            ACC16(v, w);
        }
    }
    if (j4 < 75) {
#pragma unroll
        for (int ni = 0; ni < 4; ++ni) {
            float4 o = {acc[ni][0], acc[ni][1], acc[ni][2], acc[ni][3]};
            if (do_elu) {
                o.x = o.x > 0.f ? o.x : expm1f(o.x);
                o.y = o.y > 0.f ? o.y : expm1f(o.y);
                o.z = o.z > 0.f ? o.z : expm1f(o.z);
                o.w = o.w > 0.f ? o.w : expm1f(o.w);
            }
            *reinterpret_cast<float4*>(out + ((size_t)b * CN + n0 + grp * 4 + ni) * CD + j4 * 4) = o;
        }
    }
}

extern "C" void kernel_launch(void* const* d_in, const int* in_sizes, int n_in,
                              void* d_out, int out_size, void* d_ws, size_t ws_size,
                              hipStream_t stream) {
    const int*   inputs = (const int*)d_in[0];
    const int*   HT     = (const int*)d_in[1];
    const float* emb    = (const float*)d_in[2];
    const float* w2_1   = (const float*)d_in[3];
    const float* w3_1   = (const float*)d_in[4];
    const float* a_1    = (const float*)d_in[5];
    const float* a2_1   = (const float*)d_in[6];
    const float* wc_1   = (const float*)d_in[7];
    const float* w_2    = (const float*)d_in[8];
    const float* w2_2   = (const float*)d_in[9];
    const float* w3_2   = (const float*)d_in[10];
    const float* a_2    = (const float*)d_in[11];
    const float* a2_2   = (const float*)d_in[12];
    const float* wc_2   = (const float*)d_in[13];

    char* ws = (char*)d_ws;
    float* X0           = (float*)(ws);                     // 39,321,600 B
    float* X4           = (float*)(ws + 39321600);          // 39,321,600 B
    float* edge         = (float*)(ws + 78643200);          // 20,971,520 B (EP=320)
    float* e4           = (float*)(ws + 99614720);          // 19,660,800 B
    unsigned char* HTt  = (unsigned char*)(ws + 119275520); // 16,777,216 B
    float* s1           = (float*)(ws + 136052736);         // 131,072 B
    float* p            = (float*)(ws + 136183808);         // 131,072 B
    float* e1           = (float*)(ws + 136314880);         // 131,072 B
    float* qv           = (float*)(ws + 136445952);         //  65,536 B
    // total: 136,511,488 B

    k_embed<<<9600, 256, 0, stream>>>(inputs, emb, X0);
    k_transpose<<<dim3(16, 32, 32), dim3(32, 8), 0, stream>>>(HT, HTt);

    // ---- layer 1: transfer=False, concat=True (ELU), alpha=0.1 ----
    k_gemm300<<<dim3(5, 512), 256, 0, stream>>>(X0, w2_1, X4, CB * CN, CD, CD);
    k_score<<<CB * CN / 4, 256, 0, stream>>>(X4, a_1, a2_1, wc_1, 0.1f, s1, p, CB * CN);
    k_bmax<<<CB, 1024, 0, stream>>>(s1, e1);
    k_edge_agg<<<4096, 256, 0, stream>>>(HT, e1, X0, edge);
    k_gemm300<<<dim3(5, 256), 256, 0, stream>>>(edge, w3_1, e4, CB * CE, EP, CD);
    k_q<<<CB * CE / 4, 256, 0, stream>>>(e4, a2_1, qv, CB * CE);
    k_node_attn<<<2048, 320, 0, stream>>>(HTt, p, qv, edge, 0.1f, 1, X4);   // X1 -> X4 buf

    // ---- layer 2: transfer=True, concat=False, alpha=0.2 ----
    k_gemm300<<<dim3(5, 512), 256, 0, stream>>>(X4, w2_2, X0, CB * CN, CD, CD);  // X4_2
    k_score<<<CB * CN / 4, 256, 0, stream>>>(X0, a_2, a2_2, wc_2, 0.2f, s1, p, CB * CN);
    k_bmax<<<CB, 1024, 0, stream>>>(s1, e1);
    k_gemm300<<<dim3(5, 512), 256, 0, stream>>>(X4, w_2, X0, CB * CN, CD, CD);   // XW
    k_edge_agg<<<4096, 256, 0, stream>>>(HT, e1, X0, edge);
    k_gemm300<<<dim3(5, 256), 256, 0, stream>>>(edge, w3_2, e4, CB * CE, EP, CD);
    k_q<<<CB * CE / 4, 256, 0, stream>>>(e4, a2_2, qv, CB * CE);
    k_node_attn<<<2048, 320, 0, stream>>>(HTt, p, qv, edge, 0.2f, 0, (float*)d_out);
}

// Round 5
// 673.070 us; speedup vs baseline: 1.9827x; 1.4374x over previous
//
#include <hip/hip_runtime.h>
#include <hip/hip_bf16.h>

#define CB 32
#define CN 1024
#define CE 512
#define CD 300
#define EP 320    // padded edge-row stride (floats); pad cols [300,320) are written 0
#define UCAP 320  // union-list capacity per 4-node group (mean 176, sd ~11 -> never exceeded)

// ---------- embedding gather: X[r,:] = emb[idx[r],:] ----------
__global__ void k_embed(const int* __restrict__ idx, const float* __restrict__ emb,
                        float* __restrict__ X) {
    int gid = blockIdx.x * blockDim.x + threadIdx.x;
    const int total = CB * CN * 75;   // 75 float4 per 300-float row
    if (gid >= total) return;
    int r = gid / 75, c = gid % 75;
    int e = idx[r];
    reinterpret_cast<float4*>(X)[(size_t)r * 75 + c] =
        reinterpret_cast<const float4*>(emb)[(size_t)e * 75 + c];
}

// ---------- transpose HT [B,E,N] int -> HTt [B,N,E] u8 ----------
__global__ void k_transpose(const int* __restrict__ HT, unsigned char* __restrict__ HTt) {
    __shared__ int tile[32][33];
    int b = blockIdx.z;
    int e0 = blockIdx.x * 32, n0 = blockIdx.y * 32;
    int tx = threadIdx.x, ty = threadIdx.y;
    for (int i = ty; i < 32; i += 8)
        tile[i][tx] = HT[((size_t)b * CE + e0 + i) * CN + n0 + tx];
    __syncthreads();
    for (int i = ty; i < 32; i += 8)
        HTt[((size_t)b * CN + n0 + i) * CE + e0 + tx] = (unsigned char)(tile[tx][i] > 0 ? 1 : 0);
}

// ---------- k_prep: vecs = {w2_1@a1_bot, w2_1@a2_1top, w3_1@a2_1bot,
//                            w2_2@a2_bot, w2_2@a2_2top, w3_2@a2_2bot} ----------
// (X@W)·a == X·(W@a): lets scores be computed from raw layer inputs, killing 4 GEMMs.
__global__ void k_prep(const float* __restrict__ w2_1, const float* __restrict__ w3_1,
                       const float* __restrict__ a_1, const float* __restrict__ a2_1,
                       const float* __restrict__ w2_2, const float* __restrict__ w3_2,
                       const float* __restrict__ a_2, const float* __restrict__ a2_2,
                       float* __restrict__ vecs) {
    int which = blockIdx.x;
    int t = threadIdx.x;
    if (t >= CD) return;
    const float* W; const float* v;
    switch (which) {
        case 0:  W = w2_1; v = a_1 + CD;  break;   // av1
        case 1:  W = w2_1; v = a2_1;      break;   // pv1
        case 2:  W = w3_1; v = a2_1 + CD; break;   // qv1
        case 3:  W = w2_2; v = a_2 + CD;  break;   // av2
        case 4:  W = w2_2; v = a2_2;      break;   // pv2
        default: W = w3_2; v = a2_2 + CD; break;   // qv2
    }
    float s = 0.f;
    for (int j = 0; j < CD; ++j) s += W[(size_t)t * CD + j] * v[j];
    vecs[which * CD + t] = s;
}

// ---------- C[M,300] = A[M,300(lda)] @ W[300,300], M % 64 == 0 ----------
__global__ __launch_bounds__(256) void k_gemm300(const float* __restrict__ A,
                                                 const float* __restrict__ W,
                                                 float* __restrict__ C, int M,
                                                 int lda, int ldc) {
    __shared__ float As[64][20];
    __shared__ float Ws[16][68];
    int tid = threadIdx.x;
    int n0 = blockIdx.x * 64, m0 = blockIdx.y * 64;
    int tx = tid & 15, ty = tid >> 4;
    int la_r = tid >> 2, la_c = (tid & 3) << 2;
    int lw_r = tid >> 4, lw_c = (tid & 15) << 2;
    float acc[4][4] = {};
    for (int k0 = 0; k0 < CD; k0 += 16) {
        {   // A tile 64x16
            int kc = k0 + la_c;
            const float* Ap = A + (size_t)(m0 + la_r) * lda + kc;
            float4 av;
            if (kc + 3 < CD) av = *reinterpret_cast<const float4*>(Ap);
            else {
                av.x = kc     < CD ? Ap[0] : 0.f;
                av.y = kc + 1 < CD ? Ap[1] : 0.f;
                av.z = kc + 2 < CD ? Ap[2] : 0.f;
                av.w = 0.f;
            }
            *reinterpret_cast<float4*>(&As[la_r][la_c]) = av;
        }
        {   // W tile 16x64
            int kr = k0 + lw_r;
            float4 wv = {0.f, 0.f, 0.f, 0.f};
            if (kr < CD) {
                const float* Wp = W + (size_t)kr * CD + n0 + lw_c;
                if (n0 + lw_c + 3 < CD) wv = *reinterpret_cast<const float4*>(Wp);
                else {
                    if (n0 + lw_c     < CD) wv.x = Wp[0];
                    if (n0 + lw_c + 1 < CD) wv.y = Wp[1];
                    if (n0 + lw_c + 2 < CD) wv.z = Wp[2];
                }
            }
            *reinterpret_cast<float4*>(&Ws[lw_r][lw_c]) = wv;
        }
        __syncthreads();
#pragma unroll
        for (int k = 0; k < 16; ++k) {
            float av[4];
#pragma unroll
            for (int i = 0; i < 4; ++i) av[i] = As[ty * 4 + i][k];
            float4 bv = *reinterpret_cast<const float4*>(&Ws[k][tx * 4]);
            float bb[4] = {bv.x, bv.y, bv.z, bv.w};
#pragma unroll
            for (int i = 0; i < 4; ++i)
#pragma unroll
                for (int j = 0; j < 4; ++j) acc[i][j] += av[i] * bb[j];
        }
        __syncthreads();
    }
    for (int i = 0; i < 4; ++i) {
        int m = m0 + ty * 4 + i;
        int n = n0 + tx * 4;
        float* Cp = C + (size_t)m * ldc + n;
        if (n + 3 < CD) {
            float4 v = {acc[i][0], acc[i][1], acc[i][2], acc[i][3]};
            *reinterpret_cast<float4*>(Cp) = v;
        } else {
            for (int j = 0; j < 4; ++j) if (n + j < CD) Cp[j] = acc[i][j];
        }
    }
}

// ---------- s1[r] = leaky(wc·a_top + X[r,:]·av), p[r] = X[r,:]·pv ----------
__global__ void k_score(const float* __restrict__ X, const float* __restrict__ av,
                        const float* __restrict__ pv, const float* __restrict__ wc,
                        const float* __restrict__ a_orig,
                        float alpha, float* __restrict__ s1, float* __restrict__ p, int M) {
    int gw = (blockIdx.x * blockDim.x + threadIdx.x) >> 6;
    int lane = threadIdx.x & 63;
    if (gw >= M) return;
    const float* row = X + (size_t)gw * CD;
    float d1 = 0.f, d2 = 0.f, dc = 0.f;
    for (int d = lane; d < CD; d += 64) {
        float x = row[d];
        d1 += x * av[d];
        d2 += x * pv[d];
        dc += wc[d] * a_orig[d];
    }
    for (int o = 32; o; o >>= 1) {
        d1 += __shfl_down(d1, o);
        d2 += __shfl_down(d2, o);
        dc += __shfl_down(dc, o);
    }
    if (lane == 0) {
        float v = dc + d1;
        s1[gw] = v > 0.f ? v : alpha * v;
        p[gw] = d2;
    }
}

// ---------- per-batch max over s1, e1 = exp(s1 - max) ----------
__global__ __launch_bounds__(1024) void k_bmax(const float* __restrict__ s1,
                                               float* __restrict__ e1) {
    __shared__ float red[16];
    int b = blockIdx.x, t = threadIdx.x;
    float v = s1[b * CN + t];
    float m = v;
    for (int o = 32; o; o >>= 1) m = fmaxf(m, __shfl_xor(m, o));
    if ((t & 63) == 0) red[t >> 6] = m;
    __syncthreads();
    if (t == 0) {
        float mm = red[0];
        for (int i = 1; i < 16; ++i) mm = fmaxf(mm, red[i]);
        red[0] = mm;
    }
    __syncthreads();
    e1[b * CN + t] = __expf(v - red[0]);
}

// ---------- sparse edge aggregation ----------
// One wave per (b,e): edge[b,e,:] = (sum_{n in e} e1[n] * Xs[b,n,:]) / (sum e1[n]).
__global__ __launch_bounds__(256) void k_edge_agg(const int* __restrict__ HT,
        const float* __restrict__ e1, const float* __restrict__ Xs,
        float* __restrict__ edge) {
    int gw = (blockIdx.x * blockDim.x + threadIdx.x) >> 6;   // b*CE + e
    int lane = threadIdx.x & 63;
    int b = gw >> 9;
    const int* hrow = HT + (size_t)gw * CN;
    const float* e1b = e1 + b * CN;
    const float* Xb = Xs + (size_t)b * CN * CD;
    float acc[5] = {};
    float den = 0.f;
    bool tail = lane < (CD - 256);
    int any = 0;
#pragma unroll
    for (int c = 0; c < 16; ++c) {
        int n0 = c << 6;
        int m = hrow[n0 + lane];
        float wv = e1b[n0 + lane];
        unsigned long long bal = __ballot(m != 0);
        any |= (bal != 0ull);
        while (bal) {
            int j = (int)__ffsll(bal) - 1;
            bal &= bal - 1ull;
            float w = __shfl(wv, j);
            const float* row = Xb + (size_t)(n0 + j) * CD;
            den += w;
            acc[0] += w * row[lane];
            acc[1] += w * row[lane + 64];
            acc[2] += w * row[lane + 128];
            acc[3] += w * row[lane + 192];
            if (tail) acc[4] += w * row[lane + 256];
        }
    }
    float inv = any ? 1.f / den : 0.f;
    float* erow = edge + (size_t)gw * EP;
    erow[lane]       = acc[0] * inv;
    erow[lane + 64]  = acc[1] * inv;
    erow[lane + 128] = acc[2] * inv;
    erow[lane + 192] = acc[3] * inv;
    erow[lane + 256] = tail ? acc[4] * inv : 0.f;
}

// ---------- q[e] = edge[e,:]·qv (EP-stride rows) ----------
__global__ void k_q(const float* __restrict__ E, const float* __restrict__ qvec,
                    float* __restrict__ q, int M) {
    int gw = (blockIdx.x * blockDim.x + threadIdx.x) >> 6;
    int lane = threadIdx.x & 63;
    if (gw >= M) return;
    const float* row = E + (size_t)gw * EP;
    float d2 = 0.f;
    for (int d = lane; d < CD; d += 64) d2 += row[d] * qvec[d];
    for (int o = 32; o; o >>= 1) d2 += __shfl_down(d2, o);
    if (lane == 0) q[gw] = d2;
}

// ---------- fused node attention v4: compacted weights + union list ----------
#define ACC16(vv, ww) do { \
    acc[0][0] += (ww).x * (vv).x; acc[0][1] += (ww).x * (vv).y; \
    acc[0][2] += (ww).x * (vv).z; acc[0][3] += (ww).x * (vv).w; \
    acc[1][0] += (ww).y * (vv).x; acc[1][1] += (ww).y * (vv).y; \
    acc[1][2] += (ww).y * (vv).z; acc[1][3] += (ww).y * (vv).w; \
    acc[2][0] += (ww).z * (vv).x; acc[2][1] += (ww).z * (vv).y; \
    acc[2][2] += (ww).z * (vv).z; acc[2][3] += (ww).z * (vv).w; \
    acc[3][0] += (ww).w * (vv).x; acc[3][1] += (ww).w * (vv).y; \
    acc[3][2] += (ww).w * (vv).z; acc[3][3] += (ww).w * (vv).w; \
} while (0)

__global__ __launch_bounds__(320, 8) void k_node_attn(const unsigned char* __restrict__ HTt,
        const float* __restrict__ p, const float* __restrict__ q,
        const float* __restrict__ edge, float alpha, int do_elu, float* __restrict__ out) {
    __shared__ float4 wsc[4][UCAP];                 // compacted weights (union order)
    __shared__ __align__(8) unsigned short ul[4][UCAP];
    __shared__ int ucnt_s[4], flag_s[4];
    __shared__ float gpn[16], gmx[16], gsc[16];     // per-node stats for rare slow path
    __shared__ int gct[16];
    int blk = blockIdx.x;
    int b = blk >> 6, n0 = (blk & 63) << 4;
    int tid = threadIdx.x, wv = tid >> 6, lane = tid & 63;
    const float* qb = q + b * CE;

    if (wv < 4) {
        float pn[4]; const unsigned char* mr[4];
#pragma unroll
        for (int k = 0; k < 4; ++k) {
            int n = n0 + 4 * wv + k;
            pn[k] = p[b * CN + n];
            mr[k] = HTt + ((size_t)b * CN + n) * CE;
        }
        float sc[4][8];
        int cnt[4] = {0, 0, 0, 0};
        float mx[4] = {-3.4e38f, -3.4e38f, -3.4e38f, -3.4e38f};
        int ubits = 0;
#pragma unroll
        for (int j = 0; j < 8; ++j) {
            int e = lane + (j << 6);
            float qe = qb[e];
            int many = 0;
#pragma unroll
            for (int k = 0; k < 4; ++k) {
                int m = mr[k][e];
                float v = pn[k] + qe;
                v = v > 0.f ? v : alpha * v;
                v = m ? v : -3.0e38f;   // masked -> exp underflows to 0
                cnt[k] += m; many |= m;
                mx[k] = fmaxf(mx[k], v);
                sc[k][j] = v;
            }
            ubits |= (many ? 1 : 0) << j;
        }
#pragma unroll
        for (int k = 0; k < 4; ++k) {
            for (int o = 32; o; o >>= 1) {
                mx[k] = fmaxf(mx[k], __shfl_xor(mx[k], o));
                cnt[k] += __shfl_xor(cnt[k], o);
            }
        }
        float scale[4];
#pragma unroll
        for (int k = 0; k < 4; ++k) {
            float s = 0.f;
#pragma unroll
            for (int j = 0; j < 8; ++j) { float w8 = __expf(sc[k][j] - mx[k]); sc[k][j] = w8; s += w8; }
            for (int o = 32; o; o >>= 1) s += __shfl_xor(s, o);
            scale[k] = cnt[k] > 0 ? 1.f / s : 1.f;
        }
        // order-preserving ballot compaction: union edges -> ul + compact weights -> wsc
        int base = 0;
        unsigned long long lmask = (1ull << lane) - 1ull;
#pragma unroll
        for (int j = 0; j < 8; ++j) {
            unsigned long long bal = __ballot((ubits >> j) & 1);
            if ((ubits >> j) & 1) {
                int off = base + (int)__popcll(bal & lmask);
                if (off < UCAP) {
                    ul[wv][off] = (unsigned short)(lane + (j << 6));
                    wsc[wv][off] = make_float4(sc[0][j] * scale[0], sc[1][j] * scale[1],
                                               sc[2][j] * scale[2], sc[3][j] * scale[3]);
                }
            }
            base += (int)__popcll(bal);
        }
        if (lane == 0) {
            ucnt_s[wv] = base < UCAP ? base : UCAP;
            flag_s[wv] = (cnt[0] == 0) | (cnt[1] == 0) | (cnt[2] == 0) | (cnt[3] == 0) |
                         (base > UCAP);
            gpn[wv*4+0]=pn[0]; gmx[wv*4+0]=mx[0]; gsc[wv*4+0]=scale[0]; gct[wv*4+0]=cnt[0];
            gpn[wv*4+1]=pn[1]; gmx[wv*4+1]=mx[1]; gsc[wv*4+1]=scale[1]; gct[wv*4+1]=cnt[1];
            gpn[wv*4+2]=pn[2]; gmx[wv*4+2]=mx[2]; gsc[wv*4+2]=scale[2]; gct[wv*4+2]=cnt[2];
            gpn[wv*4+3]=pn[3]; gmx[wv*4+3]=mx[3]; gsc[wv*4+3]=scale[3]; gct[wv*4+3]=cnt[3];
        }
    }
    __syncthreads();

    // phase 2: out[n0+4*grp+k, 4*j4+di] = sum_i wsc[grp][i][k] * edge[b,ul[grp][i],:]
    int grp = tid / 80;
    int j4 = tid - grp * 80;
    const float4* eb4 = reinterpret_cast<const float4*>(edge + (size_t)b * CE * EP) + j4;
    int cnt = ucnt_s[grp], bad = flag_s[grp];
    float acc[4][4] = {};
    if (!bad) {
        int i = 0;
        for (; i + 4 <= cnt; i += 4) {
            ushort4 uu = *reinterpret_cast<const ushort4*>(&ul[grp][i]);
            float4 w0 = wsc[grp][i],     w1 = wsc[grp][i + 1];
            float4 w2 = wsc[grp][i + 2], w3 = wsc[grp][i + 3];
            float4 v0 = eb4[(size_t)uu.x * 80], v1 = eb4[(size_t)uu.y * 80];
            float4 v2 = eb4[(size_t)uu.z * 80], v3 = eb4[(size_t)uu.w * 80];
            ACC16(v0, w0); ACC16(v1, w1); ACC16(v2, w2); ACC16(v3, w3);
        }
        for (; i < cnt; ++i) {
            int e = ul[grp][i];
            float4 v = eb4[(size_t)e * 80];
            float4 w = wsc[grp][i];
            ACC16(v, w);
        }
    } else {
        // rare (zero-degree node / overflow): recompute weights densely (same ops as phase 1)
        float pn0 = gpn[grp*4+0], mx0 = gmx[grp*4+0], sc0 = gsc[grp*4+0]; int ct0 = gct[grp*4+0];
        float pn1 = gpn[grp*4+1], mx1 = gmx[grp*4+1], sc1 = gsc[grp*4+1]; int ct1 = gct[grp*4+1];
        float pn2 = gpn[grp*4+2], mx2 = gmx[grp*4+2], sc2 = gsc[grp*4+2]; int ct2 = gct[grp*4+2];
        float pn3 = gpn[grp*4+3], mx3 = gmx[grp*4+3], sc3 = gsc[grp*4+3]; int ct3 = gct[grp*4+3];
        const unsigned char* hb = HTt + ((size_t)b * CN + n0 + grp * 4) * CE;
        for (int e = 0; e < CE; ++e) {
            float4 v = eb4[(size_t)e * 80];
            float qe = qb[e];
            float vv, w;
            int m;
            m = hb[e];
            vv = pn0 + qe; vv = vv > 0.f ? vv : alpha * vv;
            w = ct0 == 0 ? (1.f / CE) : (m ? __expf(vv - mx0) * sc0 : 0.f);
            acc[0][0] += w * v.x; acc[0][1] += w * v.y; acc[0][2] += w * v.z; acc[0][3] += w * v.w;
            m = hb[CE + e];
            vv = pn1 + qe; vv = vv > 0.f ? vv : alpha * vv;
            w = ct1 == 0 ? (1.f / CE) : (m ? __expf(vv - mx1) * sc1 : 0.f);
            acc[1][0] += w * v.x; acc[1][1] += w * v.y; acc[1][2] += w * v.z; acc[1][3] += w * v.w;
            m = hb[2 * CE + e];
            vv = pn2 + qe; vv = vv > 0.f ? vv : alpha * vv;
            w = ct2 == 0 ? (1.f / CE) : (m ? __expf(vv - mx2) * sc2 : 0.f);
            acc[2][0] += w * v.x; acc[2][1] += w * v.y; acc[2][2] += w * v.z; acc[2][3] += w * v.w;
            m = hb[3 * CE + e];
            vv = pn3 + qe; vv = vv > 0.f ? vv : alpha * vv;
            w = ct3 == 0 ? (1.f / CE) : (m ? __expf(vv - mx3) * sc3 : 0.f);
            acc[3][0] += w * v.x; acc[3][1] += w * v.y; acc[3][2] += w * v.z; acc[3][3] += w * v.w;
        }
    }
    if (j4 < 75) {
#pragma unroll
        for (int ni = 0; ni < 4; ++ni) {
            float4 o = {acc[ni][0], acc[ni][1], acc[ni][2], acc[ni][3]};
            if (do_elu) {
                o.x = o.x > 0.f ? o.x : expm1f(o.x);
                o.y = o.y > 0.f ? o.y : expm1f(o.y);
                o.z = o.z > 0.f ? o.z : expm1f(o.z);
                o.w = o.w > 0.f ? o.w : expm1f(o.w);
            }
            *reinterpret_cast<float4*>(out + ((size_t)b * CN + n0 + grp * 4 + ni) * CD + j4 * 4) = o;
        }
    }
}

extern "C" void kernel_launch(void* const* d_in, const int* in_sizes, int n_in,
                              void* d_out, int out_size, void* d_ws, size_t ws_size,
                              hipStream_t stream) {
    const int*   inputs = (const int*)d_in[0];
    const int*   HT     = (const int*)d_in[1];
    const float* emb    = (const float*)d_in[2];
    const float* w2_1   = (const float*)d_in[3];
    const float* w3_1   = (const float*)d_in[4];
    const float* a_1    = (const float*)d_in[5];
    const float* a2_1   = (const float*)d_in[6];
    const float* wc_1   = (const float*)d_in[7];
    const float* w_2    = (const float*)d_in[8];
    const float* w2_2   = (const float*)d_in[9];
    const float* w3_2   = (const float*)d_in[10];
    const float* a_2    = (const float*)d_in[11];
    const float* a2_2   = (const float*)d_in[12];
    const float* wc_2   = (const float*)d_in[13];

    char* ws = (char*)d_ws;
    float* big0         = (float*)(ws);                     // 39,321,600 B: X0, then X1
    float* big1         = (float*)(ws + 39321600);          // 39,321,600 B: XW (layer 2)
    float* edge         = (float*)(ws + 78643200);          // 20,971,520 B (EP=320)
    unsigned char* HTt  = (unsigned char*)(ws + 99614720);  // 16,777,216 B
    float* s1           = (float*)(ws + 116391936);         // 131,072 B
    float* p            = (float*)(ws + 116523008);         // 131,072 B
    float* e1           = (float*)(ws + 116654080);         // 131,072 B
    float* qv           = (float*)(ws + 116785152);         //  65,536 B
    float* vecs         = (float*)(ws + 116850688);         //   7,200 B
    // total: 116,857,888 B

    k_embed<<<9600, 256, 0, stream>>>(inputs, emb, big0);
    k_transpose<<<dim3(16, 32, 32), dim3(32, 8), 0, stream>>>(HT, HTt);
    k_prep<<<6, 320, 0, stream>>>(w2_1, w3_1, a_1, a2_1, w2_2, w3_2, a_2, a2_2, vecs);

    // ---- layer 1: transfer=False, concat=True (ELU), alpha=0.1 ----
    k_score<<<CB * CN / 4, 256, 0, stream>>>(big0, vecs, vecs + CD, wc_1, a_1, 0.1f, s1, p, CB * CN);
    k_bmax<<<CB, 1024, 0, stream>>>(s1, e1);
    k_edge_agg<<<4096, 256, 0, stream>>>(HT, e1, big0, edge);
    k_q<<<CB * CE / 4, 256, 0, stream>>>(edge, vecs + 2 * CD, qv, CB * CE);
    k_node_attn<<<2048, 320, 0, stream>>>(HTt, p, qv, edge, 0.1f, 1, big0);   // X1 -> big0 (X0 dead)

    // ---- layer 2: transfer=True, concat=False, alpha=0.2 ----
    k_score<<<CB * CN / 4, 256, 0, stream>>>(big0, vecs + 3 * CD, vecs + 4 * CD, wc_2, a_2, 0.2f, s1, p, CB * CN);
    k_gemm300<<<dim3(5, 512), 256, 0, stream>>>(big0, w_2, big1, CB * CN, CD, CD);   // XW = X1 @ w_2
    k_bmax<<<CB, 1024, 0, stream>>>(s1, e1);
    k_edge_agg<<<4096, 256, 0, stream>>>(HT, e1, big1, edge);
    k_q<<<CB * CE / 4, 256, 0, stream>>>(edge, vecs + 5 * CD, qv, CB * CE);
    k_node_attn<<<2048, 320, 0, stream>>>(HTt, p, qv, edge, 0.2f, 0, (float*)d_out);
}